// Round 21
// baseline (1671.384 us; speedup 1.0000x reference)
//
#include <hip/hip_runtime.h>

// Problem constants (fixed by reference)
constexpr int N_ = 2, T_ = 12, C_ = 64, H_ = 112, W_ = 112;
constexpr int HW_ = H_ * W_;
constexpr float SLOPE_ = 0.1f;
// Packed fp32 working-feats layout: [n][t][cg 0..3][HW][16ch]
constexpr int PHW_ = HW_ * 16;
constexpr long NSTW_ = (long)T_ * 4 * PHW_;

typedef short bf16x8 __attribute__((ext_vector_type(8)));
typedef float f32x16 __attribute__((ext_vector_type(16)));

__device__ __forceinline__ unsigned short f2bf(float f) {
  unsigned u = __float_as_uint(f);
  unsigned r = (u + 0x7fffu + ((u >> 16) & 1u)) >> 16;
  return (unsigned short)r;
}
__device__ __forceinline__ float bf2f(unsigned short h) {
  return __uint_as_float(((unsigned)h) << 16);
}

// ---------------------------------------------------------------------------
// Scalar bilinear (2-channel flow for f2_tot), zero-pad outside.
// ---------------------------------------------------------------------------
__device__ __forceinline__ float samp_one(const float* __restrict__ img, int y, int x) {
  if ((unsigned)x < (unsigned)W_ && (unsigned)y < (unsigned)H_)
    return img[y * W_ + x];
  return 0.f;
}

__device__ __forceinline__ float bilin(const float* __restrict__ img, float vx, float vy) {
  float x0f = floorf(vx), y0f = floorf(vy);
  int x0 = (int)x0f, y0 = (int)y0f;
  float wx = vx - x0f, wy = vy - y0f;
  float g00 = samp_one(img, y0,     x0);
  float g01 = samp_one(img, y0,     x0 + 1);
  float g10 = samp_one(img, y0 + 1, x0);
  float g11 = samp_one(img, y0 + 1, x0 + 1);
  return g00 * (1.f - wx) * (1.f - wy)
       + g01 * wx * (1.f - wy)
       + g10 * (1.f - wx) * wy
       + g11 * wx * wy;
}

// 8-channel bilinear from the packed layout: corner = 2 coalesced float4.
__device__ __forceinline__ void bilin8p(const float* __restrict__ sp, int gg,
                                        float vx, float vy, float* __restrict__ v) {
  float x0f = floorf(vx), y0f = floorf(vy);
  int x0 = (int)x0f, y0 = (int)y0f;
  float wx = vx - x0f, wy = vy - y0f;
  float w00 = (1.f - wx) * (1.f - wy), w01 = wx * (1.f - wy);
  float w10 = (1.f - wx) * wy,         w11 = wx * wy;
  bool bx0 = (unsigned)x0 < (unsigned)W_, bx1 = (unsigned)(x0 + 1) < (unsigned)W_;
  bool by0 = (unsigned)y0 < (unsigned)H_, by1 = (unsigned)(y0 + 1) < (unsigned)H_;
  float m00 = (bx0 && by0) ? w00 : 0.f;
  float m01 = (bx1 && by0) ? w01 : 0.f;
  float m10 = (bx0 && by1) ? w10 : 0.f;
  float m11 = (bx1 && by1) ? w11 : 0.f;
  int cx0 = min(max(x0, 0), W_ - 1), cx1 = min(max(x0 + 1, 0), W_ - 1);
  int cy0 = min(max(y0, 0), H_ - 1), cy1 = min(max(y0 + 1, 0), H_ - 1);
  const float* q00 = sp + ((long)cy0 * W_ + cx0) * 16 + gg * 8;
  const float* q01 = sp + ((long)cy0 * W_ + cx1) * 16 + gg * 8;
  const float* q10 = sp + ((long)cy1 * W_ + cx0) * 16 + gg * 8;
  const float* q11 = sp + ((long)cy1 * W_ + cx1) * 16 + gg * 8;
  float4 a00 = *(const float4*)q00, b00 = *(const float4*)(q00 + 4);
  float4 a01 = *(const float4*)q01, b01 = *(const float4*)(q01 + 4);
  float4 a10 = *(const float4*)q10, b10 = *(const float4*)(q10 + 4);
  float4 a11 = *(const float4*)q11, b11 = *(const float4*)(q11 + 4);
  const float* p00 = (const float*)&a00;
  const float* p01 = (const float*)&a01;
  const float* p10 = (const float*)&a10;
  const float* p11 = (const float*)&a11;
#pragma unroll
  for (int j = 0; j < 4; ++j)
    v[j] = p00[j] * m00 + p01[j] * m01 + p10[j] * m10 + p11[j] * m11;
  p00 = (const float*)&b00; p01 = (const float*)&b01;
  p10 = (const float*)&b10; p11 = (const float*)&b11;
#pragma unroll
  for (int j = 0; j < 4; ++j)
    v[4 + j] = p00[j] * m00 + p01[j] * m01 + p10[j] * m10 + p11[j] * m11;
}

// ---------------------------------------------------------------------------
// warp_coords: once per step, per (n, pixel): {vx1, vy1, vx2, vy2}.
// vx1/vy1 = coords for warp(p1, f1); vx2/vy2 = coords for warp(p2, f2_tot)
// (only valid when f2 non-null; unread otherwise). Removes the dependent
// flow-gather + f2tot chain from warp_conv1's phase 1 and dedups it across
// the KG blocks (r20: latency-bound on that chain at 17% occupancy).
// ---------------------------------------------------------------------------
__global__ __launch_bounds__(256) void warp_coords(
    const float* __restrict__ f1, const float* __restrict__ f2,
    float4* __restrict__ coords) {
  int id = blockIdx.x * 256 + threadIdx.x;
  if (id >= N_ * HW_) return;
  int hw = id % HW_;
  int n  = id / HW_;
  int x = hw % W_, y = hw / W_;
  const float* f1n = f1 + (long)n * T_ * 2 * HW_;
  float ax = (float)x + f1n[hw];
  float ay = (float)y + f1n[HW_ + hw];
  float vx2 = 0.f, vy2 = 0.f;
  if (f2) {
    const float* f2n = f2 + (long)n * T_ * 2 * HW_;
    vx2 = ax + bilin(f2n,       ax, ay);
    vy2 = ay + bilin(f2n + HW_, ax, ay);
  }
  coords[id] = float4{ax, ay, vx2, vy2};
}

// ---------------------------------------------------------------------------
// pack_feats: NCHW fp32 feats -> packed Wf [n][t][cg][HW][16].
// r20 post-mortem: r18 had contiguous 32B writes but SCALAR reads (47us);
// r19 vectorized reads but broke writes (56us). This: float4 reads +
// r18-style 32B-contiguous writes (tid*32B dense).
// ---------------------------------------------------------------------------
__global__ __launch_bounds__(256) void pack_feats(
    const float* __restrict__ feats, float* __restrict__ Wf) {
  __shared__ float sm[16][113];
  int bid = blockIdx.x;
  int y   = bid % H_;
  int cg  = (bid / H_) % 4;
  int nt  = bid / (H_ * 4);
  int tid = threadIdx.x;
  const float* src = feats + ((long)nt * C_ + cg * 16) * HW_ + (long)y * W_;
  for (int its = tid; its < 448; its += 256) {
    int c = its / 28, xq = its - c * 28;
    float4 a = *(const float4*)(src + (long)c * HW_ + xq * 4);
    sm[c][xq * 4 + 0] = a.x; sm[c][xq * 4 + 1] = a.y;
    sm[c][xq * 4 + 2] = a.z; sm[c][xq * 4 + 3] = a.w;
  }
  __syncthreads();
  if (tid < 224) {
    int px = tid >> 1, gg = tid & 1;
    float* dst = Wf + ((long)nt * 4 + cg) * PHW_ + ((long)y * W_ + px) * 16 + gg * 8;
    float4 a{sm[gg * 8 + 0][px], sm[gg * 8 + 1][px], sm[gg * 8 + 2][px], sm[gg * 8 + 3][px]};
    float4 b{sm[gg * 8 + 4][px], sm[gg * 8 + 5][px], sm[gg * 8 + 6][px], sm[gg * 8 + 7][px]};
    *(float4*)dst = a;
    *(float4*)(dst + 4) = b;
  }
}

// ---------------------------------------------------------------------------
// pack_w: W (64, IC, 3, 3) fp32 -> MFMA A-fragment order, split hi/lo bf16.
// ---------------------------------------------------------------------------
__global__ __launch_bounds__(256) void pack_w(
    const float* __restrict__ W, short* __restrict__ whi, short* __restrict__ wlo,
    int ICBC) {
  int id = blockIdx.x * 256 + threadIdx.x;
  int total = 2 * 9 * ICBC * 64 * 8;
  if (id >= total) return;
  int r    = id & 7;
  int lane = (id >> 3) & 63;
  int rest = id >> 9;
  int icb  = rest % ICBC;
  int mtt  = rest / ICBC;
  int tap  = mtt % 9;
  int mt   = mtt / 9;
  int oc = mt * 32 + (lane & 31);
  int ic = icb * 16 + ((lane >> 5) << 3) + r;
  int ky = tap / 3, kx = tap % 3;
  int IC = ICBC * 16;
  float v = W[(((long)oc * IC + ic) * 3 + ky) * 3 + kx];
  unsigned short h = f2bf(v);
  unsigned short l = f2bf(v - bf2f(h));
  whi[id] = (short)h;
  wlo[id] = (short)l;
}

// ---------------------------------------------------------------------------
// warp_conv1: fused warp+pack+conv1 partial (r20 geometry: KG1=4, icbs
// {kg,kg+4,kg+8} = {curr,p1,p2} balanced, 41.5KB LDS, 896 blocks).
// Phase 1 now reads PRECOMPUTED coords (1 float4) -> 8 corner float4s:
// dependent chain halved, f2tot dedup'd across kg.
// ---------------------------------------------------------------------------
__global__ __launch_bounds__(256) void warp_conv1(
    const float* __restrict__ currP,
    const float* __restrict__ p1P,
    const float* __restrict__ p2P,
    const float4* __restrict__ coords,
    const short* __restrict__ whi, const short* __restrict__ wlo,
    float* __restrict__ part1) {
  constexpr int ICBT = 12, KG = 4, NICB = 3;
  __shared__ alignas(16) short sx[NICB * 6912];   // 41472 B
  const int tid  = threadIdx.x;
  const int lane = tid & 63;
  const int wid  = tid >> 6;
  const int mt   = wid & 1;
  const int rp   = wid >> 1;
  const int g    = (lane >> 5) & 1;
  const int bx   = blockIdx.x * 32;
  const int by4  = blockIdx.y * 4;
  const int z    = blockIdx.z;
  const int kg   = z % KG;
  const int n    = z / KG;
  const long fnp = (long)n * NSTW_;

  const float* srcs[3] = { currP, p1P ? p1P : currP, p2P ? p2P : currP };
  const bool wf[3] = { false, p1P != nullptr, p2P != nullptr };

  // --- Phase 1: warp into LDS (sample s = [ii][r 0..5][k 0..71]) ---
#pragma unroll
  for (int it = 0; it < 6; ++it) {
    int s = it * 256 + tid;
    if (s < NICB * 432) {
      int ii  = s / 432;
      int rem = s - ii * 432;
      int r   = rem / 72;
      int k   = rem - r * 72;
      int slot = k >> 1, gg = k & 1;
      int gy = by4 + r - 1;
      int gx = bx + slot - 1;
      int icb = kg + 4 * ii;            // {kg, kg+4, kg+8} = {c, p1, p2}
      int stype = icb >> 2;
      int cg  = icb & 3;
      const float* sp = srcs[stype] + fnp + (long)cg * PHW_;
      float v[8];
      bool inimg = ((unsigned)gy < (unsigned)H_) && ((unsigned)gx < (unsigned)W_);
      if (!inimg) {
#pragma unroll
        for (int j = 0; j < 8; ++j) v[j] = 0.f;
      } else if (!wf[stype]) {
        const float* q = sp + ((long)gy * W_ + gx) * 16 + gg * 8;
        float4 a = *(const float4*)q, b = *(const float4*)(q + 4);
        v[0] = a.x; v[1] = a.y; v[2] = a.z; v[3] = a.w;
        v[4] = b.x; v[5] = b.y; v[6] = b.z; v[7] = b.w;
      } else {
        float4 c = coords[(long)n * HW_ + (long)gy * W_ + gx];
        float vx = (stype == 1) ? c.x : c.z;
        float vy = (stype == 1) ? c.y : c.w;
        bilin8p(sp, gg, vx, vy, v);
      }
      unsigned hh[8], ll[8];
#pragma unroll
      for (int j = 0; j < 8; ++j) {
        hh[j] = f2bf(v[j]);
        ll[j] = f2bf(v[j] - bf2f((unsigned short)hh[j]));
      }
      uint4 uh{hh[0] | (hh[1] << 16), hh[2] | (hh[3] << 16),
               hh[4] | (hh[5] << 16), hh[6] | (hh[7] << 16)};
      uint4 ul{ll[0] | (ll[1] << 16), ll[2] | (ll[3] << 16),
               ll[4] | (ll[5] << 16), ll[6] | (ll[7] << 16)};
      short* b = sx + ii * 6912 + r * 576 + slot * 16 + gg * 8;
      *(uint4*)b = uh;
      *(uint4*)(b + 3456) = ul;
    }
  }
  __syncthreads();

  // --- Phase 2: MFMA loop (2 output rows/wave), permuted weight icb ---
  f32x16 accA0, accB0, accA1, accB1;
#pragma unroll
  for (int i = 0; i < 16; ++i) { accA0[i] = 0.f; accB0[i] = 0.f; accA1[i] = 0.f; accB1[i] = 0.f; }

#pragma unroll
  for (int ii = 0; ii < NICB; ++ii) {
    const int icb = kg + 4 * ii;
#pragma unroll
    for (int tap = 0; tap < 9; ++tap) {
      const int dy = tap / 3, dx = tap % 3;
      const int sbase = ii * 6912 + (2 * rp + dy) * 576 + ((lane & 31) + dx) * 16 + g * 8;
      bf16x8 xh0 = *(const bf16x8*)&sx[sbase];
      bf16x8 xl0 = *(const bf16x8*)&sx[sbase + 3456];
      bf16x8 xh1 = *(const bf16x8*)&sx[sbase + 576];
      bf16x8 xl1 = *(const bf16x8*)&sx[sbase + 3456 + 576];
      long wi = ((long)((mt * 9 + tap) * ICBT + icb)) * 512 + lane * 8;
      bf16x8 wh = *(const bf16x8*)(whi + wi);
      bf16x8 wl = *(const bf16x8*)(wlo + wi);
      accA0 = __builtin_amdgcn_mfma_f32_32x32x16_bf16(wh, xh0, accA0, 0, 0, 0);
      accA1 = __builtin_amdgcn_mfma_f32_32x32x16_bf16(wh, xh1, accA1, 0, 0, 0);
      accB0 = __builtin_amdgcn_mfma_f32_32x32x16_bf16(wl, xh0, accB0, 0, 0, 0);
      accB1 = __builtin_amdgcn_mfma_f32_32x32x16_bf16(wl, xh1, accB1, 0, 0, 0);
      accB0 = __builtin_amdgcn_mfma_f32_32x32x16_bf16(wh, xl0, accB0, 0, 0, 0);
      accB1 = __builtin_amdgcn_mfma_f32_32x32x16_bf16(wh, xl1, accB1, 0, 0, 0);
    }
  }

  int pxg = bx + (lane & 31);
  if (pxg < W_) {
    long b0 = ((long)z * HW_ + (long)(by4 + 2 * rp) * W_ + pxg) * 64 + mt * 32 + g * 4;
    long b1v = b0 + (long)W_ * 64;
    float* q0 = part1 + b0;
    float* q1 = part1 + b1v;
#pragma unroll
    for (int qq = 0; qq < 4; ++qq) {
      *(float4*)(q0 + qq * 8) = float4{accA0[qq*4+0] + accB0[qq*4+0], accA0[qq*4+1] + accB0[qq*4+1],
                                       accA0[qq*4+2] + accB0[qq*4+2], accA0[qq*4+3] + accB0[qq*4+3]};
      *(float4*)(q1 + qq * 8) = float4{accA1[qq*4+0] + accB1[qq*4+0], accA1[qq*4+1] + accB1[qq*4+1],
                                       accA1[qq*4+2] + accB1[qq*4+2], accA1[qq*4+3] + accB1[qq*4+3]};
    }
  }
}

// ---------------------------------------------------------------------------
// conv2f: fused combine1 + conv2 partial. Staging computes h1 on the fly
// from 4 pixel-packed conv1 partials (+b1, lrelu, hi/lo split -> LDS).
// ---------------------------------------------------------------------------
__global__ __launch_bounds__(256) void conv2f(
    const float* __restrict__ part1, const float* __restrict__ b1,
    const short* __restrict__ whi, const short* __restrict__ wlo,
    float* __restrict__ part2) {
  constexpr int ICBT = 4, KG1 = 4;
  __shared__ alignas(16) short sx[6912];
  const int tid  = threadIdx.x;
  const int lane = tid & 63;
  const int wid  = tid >> 6;
  const int mt   = wid & 1;
  const int rp   = wid >> 1;
  const int g    = (lane >> 5) & 1;
  const int bx   = blockIdx.x * 32;
  const int by4  = blockIdx.y * 4;
  const int z    = blockIdx.z;
  const int kg   = z & 3;          // icb = cg
  const int n    = z >> 2;
  const int cg   = kg;

  float4 bA = *(const float4*)(b1 + cg * 16);
  float4 bB = *(const float4*)(b1 + cg * 16 + 4);
  float4 bC = *(const float4*)(b1 + cg * 16 + 8);
  float4 bD = *(const float4*)(b1 + cg * 16 + 12);

  // --- Staging: h1 tile computed from partials ---
#pragma unroll
  for (int it = 0; it < 2; ++it) {
    int s = it * 256 + tid;
    if (s < 432) {
      int r = s / 72, k = s - r * 72;
      int slot = k >> 1, gg = k & 1;
      int gy = by4 + r - 1;
      int gx = bx + slot - 1;
      float v[8];
      if (((unsigned)gy < (unsigned)H_) && ((unsigned)gx < (unsigned)W_)) {
        float4 sa = gg ? bC : bA;
        float4 sb = gg ? bD : bB;
        v[0] = sa.x; v[1] = sa.y; v[2] = sa.z; v[3] = sa.w;
        v[4] = sb.x; v[5] = sb.y; v[6] = sb.z; v[7] = sb.w;
        long pxo = ((long)gy * W_ + gx) * 64 + cg * 16 + gg * 8;
#pragma unroll
        for (int k1 = 0; k1 < KG1; ++k1) {
          const float* q = part1 + (long)(n * KG1 + k1) * HW_ * 64 + pxo;
          float4 a = *(const float4*)q, b = *(const float4*)(q + 4);
          v[0] += a.x; v[1] += a.y; v[2] += a.z; v[3] += a.w;
          v[4] += b.x; v[5] += b.y; v[6] += b.z; v[7] += b.w;
        }
#pragma unroll
        for (int j = 0; j < 8; ++j) v[j] = v[j] > 0.f ? v[j] : v[j] * SLOPE_;
      } else {
#pragma unroll
        for (int j = 0; j < 8; ++j) v[j] = 0.f;
      }
      unsigned hh[8], ll[8];
#pragma unroll
      for (int j = 0; j < 8; ++j) {
        hh[j] = f2bf(v[j]);
        ll[j] = f2bf(v[j] - bf2f((unsigned short)hh[j]));
      }
      uint4 uh{hh[0] | (hh[1] << 16), hh[2] | (hh[3] << 16),
               hh[4] | (hh[5] << 16), hh[6] | (hh[7] << 16)};
      uint4 ul{ll[0] | (ll[1] << 16), ll[2] | (ll[3] << 16),
               ll[4] | (ll[5] << 16), ll[6] | (ll[7] << 16)};
      short* b = sx + r * 576 + slot * 16 + gg * 8;
      *(uint4*)b = uh;
      *(uint4*)(b + 3456) = ul;
    }
  }
  __syncthreads();

  // --- MFMA loop ---
  f32x16 accA0, accB0, accA1, accB1;
#pragma unroll
  for (int i = 0; i < 16; ++i) { accA0[i] = 0.f; accB0[i] = 0.f; accA1[i] = 0.f; accB1[i] = 0.f; }

#pragma unroll
  for (int tap = 0; tap < 9; ++tap) {
    const int dy = tap / 3, dx = tap % 3;
    const int sbase = (2 * rp + dy) * 576 + ((lane & 31) + dx) * 16 + g * 8;
    bf16x8 xh0 = *(const bf16x8*)&sx[sbase];
    bf16x8 xl0 = *(const bf16x8*)&sx[sbase + 3456];
    bf16x8 xh1 = *(const bf16x8*)&sx[sbase + 576];
    bf16x8 xl1 = *(const bf16x8*)&sx[sbase + 3456 + 576];
    long wi = ((long)((mt * 9 + tap) * ICBT + kg)) * 512 + lane * 8;
    bf16x8 wh = *(const bf16x8*)(whi + wi);
    bf16x8 wl = *(const bf16x8*)(wlo + wi);
    accA0 = __builtin_amdgcn_mfma_f32_32x32x16_bf16(wh, xh0, accA0, 0, 0, 0);
    accA1 = __builtin_amdgcn_mfma_f32_32x32x16_bf16(wh, xh1, accA1, 0, 0, 0);
    accB0 = __builtin_amdgcn_mfma_f32_32x32x16_bf16(wl, xh0, accB0, 0, 0, 0);
    accB1 = __builtin_amdgcn_mfma_f32_32x32x16_bf16(wl, xh1, accB1, 0, 0, 0);
    accB0 = __builtin_amdgcn_mfma_f32_32x32x16_bf16(wh, xl0, accB0, 0, 0, 0);
    accB1 = __builtin_amdgcn_mfma_f32_32x32x16_bf16(wh, xl1, accB1, 0, 0, 0);
  }

  int pxg = bx + (lane & 31);
  if (pxg < W_) {
    long b0 = ((long)z * HW_ + (long)(by4 + 2 * rp) * W_ + pxg) * 64 + mt * 32 + g * 4;
    long b1v = b0 + (long)W_ * 64;
    float* q0 = part2 + b0;
    float* q1 = part2 + b1v;
#pragma unroll
    for (int qq = 0; qq < 4; ++qq) {
      *(float4*)(q0 + qq * 8) = float4{accA0[qq*4+0] + accB0[qq*4+0], accA0[qq*4+1] + accB0[qq*4+1],
                                       accA0[qq*4+2] + accB0[qq*4+2], accA0[qq*4+3] + accB0[qq*4+3]};
      *(float4*)(q1 + qq * 8) = float4{accA1[qq*4+0] + accB1[qq*4+0], accA1[qq*4+1] + accB1[qq*4+1],
                                       accA1[qq*4+2] + accB1[qq*4+2], accA1[qq*4+3] + accB1[qq*4+3]};
    }
  }
}

// ---------------------------------------------------------------------------
// combine2p: final = sum_kg part2 + b2 + resid(Wf packed); writes Wf and
// NCHW d_out.
// ---------------------------------------------------------------------------
template <int KG>
__global__ __launch_bounds__(256) void combine2p(
    const float* __restrict__ part2, const float* __restrict__ bias,
    float* __restrict__ WfT,   // packed t-slice, n-stride NSTW_
    float* __restrict__ out) { // NCHW, t-slice offset pre-added
  __shared__ float sm[16][113];
  int bid = blockIdx.x;
  int y   = bid % H_;
  int cg  = (bid / H_) % 4;
  int n   = bid / (H_ * 4);
  int tid = threadIdx.x;
  if (tid < 224) {
    int px = tid >> 1, gg = tid & 1;
    const float* bp = bias + cg * 16 + gg * 8;
    float v[8];
#pragma unroll
    for (int j = 0; j < 8; ++j) v[j] = bp[j];
    long pxo = ((long)y * W_ + px) * 64 + cg * 16 + gg * 8;
#pragma unroll
    for (int k = 0; k < KG; ++k) {
      const float* q = part2 + (long)(n * KG + k) * HW_ * 64 + pxo;
      float4 a = *(const float4*)q, b = *(const float4*)(q + 4);
      v[0] += a.x; v[1] += a.y; v[2] += a.z; v[3] += a.w;
      v[4] += b.x; v[5] += b.y; v[6] += b.z; v[7] += b.w;
    }
    float* q = WfT + (long)n * NSTW_ + (long)cg * PHW_ + ((long)y * W_ + px) * 16 + gg * 8;
    float4 ra = *(const float4*)q, rb = *(const float4*)(q + 4);
    v[0] += ra.x; v[1] += ra.y; v[2] += ra.z; v[3] += ra.w;
    v[4] += rb.x; v[5] += rb.y; v[6] += rb.z; v[7] += rb.w;
    *(float4*)q = float4{v[0], v[1], v[2], v[3]};
    *(float4*)(q + 4) = float4{v[4], v[5], v[6], v[7]};
#pragma unroll
    for (int j = 0; j < 8; ++j) sm[gg * 8 + j][px] = v[j];
  }
  __syncthreads();
  for (int i = tid; i < 16 * 112; i += 256) {
    int c = i / 112, x = i - c * 112;
    out[(long)n * T_ * C_ * HW_ + (long)(cg * 16 + c) * HW_ + (long)y * W_ + x] = sm[c][x];
  }
}

// ---------------------------------------------------------------------------
// Host-side orchestration
// ---------------------------------------------------------------------------
constexpr int KG1 = 4;
constexpr int KG2 = 4;

struct Bufs {
  float* part1; float* part2; float* Wf; float4* coords;
  short *w1hi, *w1lo, *w2hi, *w2lo;
};

static void run_step(float* out, const float* flows, int t, bool fwd, int i,
                     const float* b1, const float* b2, const Bufs& B,
                     hipStream_t stream) {
  const float* currP = B.Wf + (long)t * 4 * PHW_;
  const float* p1P = nullptr;
  const float* p2P = nullptr;
  const float* f1 = nullptr;
  const float* f2 = nullptr;
  if (fwd) {
    if (t >= 1) { p1P = B.Wf + (long)(t - 1) * 4 * PHW_; f1 = flows + (long)(t - 1) * 2 * HW_; }
    if (t >= 2) { p2P = B.Wf + (long)(t - 2) * 4 * PHW_; f2 = flows + (long)(t - 2) * 2 * HW_; }
  } else {
    if (i >= 1) { p1P = B.Wf + (long)(t + 1) * 4 * PHW_; f1 = flows + (long)(t + 1) * 2 * HW_; }
    if (i >= 2) { p2P = B.Wf + (long)(t + 2) * 4 * PHW_; f2 = flows + (long)(t + 2) * 2 * HW_; }
  }

  if (f1) {
    warp_coords<<<(N_ * HW_ + 255) / 256, 256, 0, stream>>>(f1, f2, B.coords);
  }
  warp_conv1<<<dim3(4, 28, N_ * KG1), 256, 0, stream>>>(
      currP, p1P, p2P, B.coords, B.w1hi, B.w1lo, B.part1);
  conv2f<<<dim3(4, 28, N_ * KG2), 256, 0, stream>>>(
      B.part1, b1, B.w2hi, B.w2lo, B.part2);
  combine2p<KG2><<<N_ * 4 * H_, 256, 0, stream>>>(
      B.part2, b2, B.Wf + (long)t * 4 * PHW_, out + (long)t * C_ * HW_);
}

extern "C" void kernel_launch(void* const* d_in, const int* in_sizes, int n_in,
                              void* d_out, int out_size, void* d_ws, size_t ws_size,
                              hipStream_t stream) {
  const float* feats = (const float*)d_in[0];
  const float* fflow = (const float*)d_in[1];
  const float* bflow = (const float*)d_in[2];
  const float* W1 = (const float*)d_in[3];
  const float* b1 = (const float*)d_in[4];
  const float* W2 = (const float*)d_in[5];
  const float* b2 = (const float*)d_in[6];
  float* out = (float*)d_out;

  char* p = (char*)d_ws;
  auto carve = [&](size_t bytes) {
    void* r = (void*)p;
    p += (bytes + 255) & ~(size_t)255;
    return r;
  };
  Bufs B;
  B.part1  = (float*)carve(sizeof(float) * (size_t)KG1 * N_ * HW_ * 64);
  B.part2  = (float*)carve(sizeof(float) * (size_t)KG2 * N_ * HW_ * 64);
  B.Wf     = (float*)carve(sizeof(float) * (size_t)N_ * T_ * 4 * PHW_);
  B.coords = (float4*)carve(sizeof(float4) * (size_t)N_ * HW_);
  B.w1hi   = (short*)carve(2 * (size_t)(2 * 9 * 12 * 64 * 8));
  B.w1lo   = (short*)carve(2 * (size_t)(2 * 9 * 12 * 64 * 8));
  B.w2hi   = (short*)carve(2 * (size_t)(2 * 9 * 4 * 64 * 8));
  B.w2lo   = (short*)carve(2 * (size_t)(2 * 9 * 4 * 64 * 8));

  // Prologue: pack feats into the working layout; weights.
  pack_feats<<<N_ * T_ * 4 * H_, 256, 0, stream>>>(feats, B.Wf);
  pack_w<<<(2 * 9 * 12 * 64 * 8 + 255) / 256, 256, 0, stream>>>(W1, B.w1hi, B.w1lo, 12);
  pack_w<<<(2 * 9 * 4 * 64 * 8 + 255) / 256, 256, 0, stream>>>(W2, B.w2hi, B.w2lo, 4);

  for (int t = 0; t < T_; ++t)
    run_step(out, fflow, t, true, t, b1, b2, B, stream);
  for (int i = 0; i < T_; ++i) {
    int t = T_ - 1 - i;
    run_step(out, bflow, t, false, i, b1, b2, B, stream);
  }
}

// Round 22
// 1588.573 us; speedup vs baseline: 1.0521x; 1.0521x over previous
//
#include <hip/hip_runtime.h>

// Problem constants (fixed by reference)
constexpr int N_ = 2, T_ = 12, C_ = 64, H_ = 112, W_ = 112;
constexpr int HW_ = H_ * W_;
constexpr float SLOPE_ = 0.1f;
// Packed fp32 working-feats layout: [n][t][cg 0..3][HW][16ch]
constexpr int PHW_ = HW_ * 16;
constexpr long NSTW_ = (long)T_ * 4 * PHW_;

typedef short bf16x8 __attribute__((ext_vector_type(8)));
typedef float f32x16 __attribute__((ext_vector_type(16)));

__device__ __forceinline__ unsigned short f2bf(float f) {
  unsigned u = __float_as_uint(f);
  unsigned r = (u + 0x7fffu + ((u >> 16) & 1u)) >> 16;
  return (unsigned short)r;
}
__device__ __forceinline__ float bf2f(unsigned short h) {
  return __uint_as_float(((unsigned)h) << 16);
}

// ---------------------------------------------------------------------------
// Scalar bilinear (2-channel flow for f2_tot), zero-pad outside.
// ---------------------------------------------------------------------------
__device__ __forceinline__ float samp_one(const float* __restrict__ img, int y, int x) {
  if ((unsigned)x < (unsigned)W_ && (unsigned)y < (unsigned)H_)
    return img[y * W_ + x];
  return 0.f;
}

__device__ __forceinline__ float bilin(const float* __restrict__ img, float vx, float vy) {
  float x0f = floorf(vx), y0f = floorf(vy);
  int x0 = (int)x0f, y0 = (int)y0f;
  float wx = vx - x0f, wy = vy - y0f;
  float g00 = samp_one(img, y0,     x0);
  float g01 = samp_one(img, y0,     x0 + 1);
  float g10 = samp_one(img, y0 + 1, x0);
  float g11 = samp_one(img, y0 + 1, x0 + 1);
  return g00 * (1.f - wx) * (1.f - wy)
       + g01 * wx * (1.f - wy)
       + g10 * (1.f - wx) * wy
       + g11 * wx * wy;
}

// 8-channel bilinear from the packed layout: corner = 2 coalesced float4.
__device__ __forceinline__ void bilin8p(const float* __restrict__ sp, int gg,
                                        float vx, float vy, float* __restrict__ v) {
  float x0f = floorf(vx), y0f = floorf(vy);
  int x0 = (int)x0f, y0 = (int)y0f;
  float wx = vx - x0f, wy = vy - y0f;
  float w00 = (1.f - wx) * (1.f - wy), w01 = wx * (1.f - wy);
  float w10 = (1.f - wx) * wy,         w11 = wx * wy;
  bool bx0 = (unsigned)x0 < (unsigned)W_, bx1 = (unsigned)(x0 + 1) < (unsigned)W_;
  bool by0 = (unsigned)y0 < (unsigned)H_, by1 = (unsigned)(y0 + 1) < (unsigned)H_;
  float m00 = (bx0 && by0) ? w00 : 0.f;
  float m01 = (bx1 && by0) ? w01 : 0.f;
  float m10 = (bx0 && by1) ? w10 : 0.f;
  float m11 = (bx1 && by1) ? w11 : 0.f;
  int cx0 = min(max(x0, 0), W_ - 1), cx1 = min(max(x0 + 1, 0), W_ - 1);
  int cy0 = min(max(y0, 0), H_ - 1), cy1 = min(max(y0 + 1, 0), H_ - 1);
  const float* q00 = sp + ((long)cy0 * W_ + cx0) * 16 + gg * 8;
  const float* q01 = sp + ((long)cy0 * W_ + cx1) * 16 + gg * 8;
  const float* q10 = sp + ((long)cy1 * W_ + cx0) * 16 + gg * 8;
  const float* q11 = sp + ((long)cy1 * W_ + cx1) * 16 + gg * 8;
  float4 a00 = *(const float4*)q00, b00 = *(const float4*)(q00 + 4);
  float4 a01 = *(const float4*)q01, b01 = *(const float4*)(q01 + 4);
  float4 a10 = *(const float4*)q10, b10 = *(const float4*)(q10 + 4);
  float4 a11 = *(const float4*)q11, b11 = *(const float4*)(q11 + 4);
  const float* p00 = (const float*)&a00;
  const float* p01 = (const float*)&a01;
  const float* p10 = (const float*)&a10;
  const float* p11 = (const float*)&a11;
#pragma unroll
  for (int j = 0; j < 4; ++j)
    v[j] = p00[j] * m00 + p01[j] * m01 + p10[j] * m10 + p11[j] * m11;
  p00 = (const float*)&b00; p01 = (const float*)&b01;
  p10 = (const float*)&b10; p11 = (const float*)&b11;
#pragma unroll
  for (int j = 0; j < 4; ++j)
    v[4 + j] = p00[j] * m00 + p01[j] * m01 + p10[j] * m10 + p11[j] * m11;
}

// ---------------------------------------------------------------------------
// warp_coords_all: coords depend ONLY on input flows (not the recurrent
// feats) -> compute ALL 24 (dir,t) sets once in the prologue (r21: per-step
// warp_coords dispatches exactly cancelled the warp_conv1 gain).
// Set sid: fwd t = sid (valid t>=1, f1 = fflow[t-1], f2 = fflow[t-2] if t>=2);
// bwd t = sid-12 (valid t<=10, f1 = bflow[t+1], f2 = bflow[t+2] if t<=9).
// coords[sid][n][hw] = {vx1, vy1, vx2, vy2}.
// ---------------------------------------------------------------------------
__global__ __launch_bounds__(256) void warp_coords_all(
    const float* __restrict__ fflow, const float* __restrict__ bflow,
    float4* __restrict__ coords) {
  long id = (long)blockIdx.x * 256 + threadIdx.x;
  long total = (long)24 * N_ * HW_;
  if (id >= total) return;
  int hw  = (int)(id % HW_);
  int n   = (int)((id / HW_) % N_);
  int sid = (int)(id / ((long)N_ * HW_));
  bool fwd = sid < 12;
  int t = fwd ? sid : sid - 12;
  const float* flows = fwd ? fflow : bflow;
  const float* f1 = nullptr;
  const float* f2 = nullptr;
  if (fwd) {
    if (t >= 1) f1 = flows + (long)(t - 1) * 2 * HW_;
    if (t >= 2) f2 = flows + (long)(t - 2) * 2 * HW_;
  } else {
    if (t <= 10) f1 = flows + (long)(t + 1) * 2 * HW_;
    if (t <= 9)  f2 = flows + (long)(t + 2) * 2 * HW_;
  }
  if (!f1) return;
  int x = hw % W_, y = hw / W_;
  const float* f1n = f1 + (long)n * T_ * 2 * HW_;
  float ax = (float)x + f1n[hw];
  float ay = (float)y + f1n[HW_ + hw];
  float vx2 = 0.f, vy2 = 0.f;
  if (f2) {
    const float* f2n = f2 + (long)n * T_ * 2 * HW_;
    vx2 = ax + bilin(f2n,       ax, ay);
    vy2 = ay + bilin(f2n + HW_, ax, ay);
  }
  coords[((long)sid * N_ + n) * HW_ + hw] = float4{ax, ay, vx2, vy2};
}

// ---------------------------------------------------------------------------
// pack_feats: NCHW fp32 feats -> packed Wf [n][t][cg][HW][16].
// float4 reads + 32B-contiguous writes.
// ---------------------------------------------------------------------------
__global__ __launch_bounds__(256) void pack_feats(
    const float* __restrict__ feats, float* __restrict__ Wf) {
  __shared__ float sm[16][113];
  int bid = blockIdx.x;
  int y   = bid % H_;
  int cg  = (bid / H_) % 4;
  int nt  = bid / (H_ * 4);
  int tid = threadIdx.x;
  const float* src = feats + ((long)nt * C_ + cg * 16) * HW_ + (long)y * W_;
  for (int its = tid; its < 448; its += 256) {
    int c = its / 28, xq = its - c * 28;
    float4 a = *(const float4*)(src + (long)c * HW_ + xq * 4);
    sm[c][xq * 4 + 0] = a.x; sm[c][xq * 4 + 1] = a.y;
    sm[c][xq * 4 + 2] = a.z; sm[c][xq * 4 + 3] = a.w;
  }
  __syncthreads();
  if (tid < 224) {
    int px = tid >> 1, gg = tid & 1;
    float* dst = Wf + ((long)nt * 4 + cg) * PHW_ + ((long)y * W_ + px) * 16 + gg * 8;
    float4 a{sm[gg * 8 + 0][px], sm[gg * 8 + 1][px], sm[gg * 8 + 2][px], sm[gg * 8 + 3][px]};
    float4 b{sm[gg * 8 + 4][px], sm[gg * 8 + 5][px], sm[gg * 8 + 6][px], sm[gg * 8 + 7][px]};
    *(float4*)dst = a;
    *(float4*)(dst + 4) = b;
  }
}

// ---------------------------------------------------------------------------
// pack_w: W (64, IC, 3, 3) fp32 -> MFMA A-fragment order, split hi/lo bf16.
// ---------------------------------------------------------------------------
__global__ __launch_bounds__(256) void pack_w(
    const float* __restrict__ W, short* __restrict__ whi, short* __restrict__ wlo,
    int ICBC) {
  int id = blockIdx.x * 256 + threadIdx.x;
  int total = 2 * 9 * ICBC * 64 * 8;
  if (id >= total) return;
  int r    = id & 7;
  int lane = (id >> 3) & 63;
  int rest = id >> 9;
  int icb  = rest % ICBC;
  int mtt  = rest / ICBC;
  int tap  = mtt % 9;
  int mt   = mtt / 9;
  int oc = mt * 32 + (lane & 31);
  int ic = icb * 16 + ((lane >> 5) << 3) + r;
  int ky = tap / 3, kx = tap % 3;
  int IC = ICBC * 16;
  float v = W[(((long)oc * IC + ic) * 3 + ky) * 3 + kx];
  unsigned short h = f2bf(v);
  unsigned short l = f2bf(v - bf2f(h));
  whi[id] = (short)h;
  wlo[id] = (short)l;
}

// ---------------------------------------------------------------------------
// warp_conv1: fused warp+pack+conv1 partial. KG1=6 (r19-vs-r20: measured
// better than KG1=4 — 13.8KB LDS, 1344 blocks beats fewer/fatter blocks),
// icbs {kg, kg+6}, precomputed coords (1 float4 -> 8 corner float4s).
// ---------------------------------------------------------------------------
__global__ __launch_bounds__(256) void warp_conv1(
    const float* __restrict__ currP,
    const float* __restrict__ p1P,
    const float* __restrict__ p2P,
    const float4* __restrict__ coords,   // set base: [n][HW]
    const short* __restrict__ whi, const short* __restrict__ wlo,
    float* __restrict__ part1) {
  constexpr int ICBT = 12, KG = 6, NICB = 2;
  __shared__ alignas(16) short sx[NICB * 6912];   // 13824 B
  const int tid  = threadIdx.x;
  const int lane = tid & 63;
  const int wid  = tid >> 6;
  const int mt   = wid & 1;
  const int rp   = wid >> 1;
  const int g    = (lane >> 5) & 1;
  const int bx   = blockIdx.x * 32;
  const int by4  = blockIdx.y * 4;
  const int z    = blockIdx.z;
  const int kg   = z % KG;
  const int n    = z / KG;
  const long fnp = (long)n * NSTW_;

  const float* srcs[3] = { currP, p1P ? p1P : currP, p2P ? p2P : currP };
  const bool wf[3] = { false, p1P != nullptr, p2P != nullptr };

  // --- Phase 1: warp into LDS (sample s = [ii][r 0..5][k 0..71]) ---
#pragma unroll
  for (int it = 0; it < 4; ++it) {
    int s = it * 256 + tid;
    if (s < NICB * 432) {
      int ii  = s / 432;
      int rem = s - ii * 432;
      int r   = rem / 72;
      int k   = rem - r * 72;
      int slot = k >> 1, gg = k & 1;
      int gy = by4 + r - 1;
      int gx = bx + slot - 1;
      int icb = kg + 6 * ii;            // {kg, kg+6}
      int stype = icb >> 2;
      int cg  = icb & 3;
      const float* sp = srcs[stype] + fnp + (long)cg * PHW_;
      float v[8];
      bool inimg = ((unsigned)gy < (unsigned)H_) && ((unsigned)gx < (unsigned)W_);
      if (!inimg) {
#pragma unroll
        for (int j = 0; j < 8; ++j) v[j] = 0.f;
      } else if (!wf[stype]) {
        const float* q = sp + ((long)gy * W_ + gx) * 16 + gg * 8;
        float4 a = *(const float4*)q, b = *(const float4*)(q + 4);
        v[0] = a.x; v[1] = a.y; v[2] = a.z; v[3] = a.w;
        v[4] = b.x; v[5] = b.y; v[6] = b.z; v[7] = b.w;
      } else {
        float4 c = coords[(long)n * HW_ + (long)gy * W_ + gx];
        float vx = (stype == 1) ? c.x : c.z;
        float vy = (stype == 1) ? c.y : c.w;
        bilin8p(sp, gg, vx, vy, v);
      }
      unsigned hh[8], ll[8];
#pragma unroll
      for (int j = 0; j < 8; ++j) {
        hh[j] = f2bf(v[j]);
        ll[j] = f2bf(v[j] - bf2f((unsigned short)hh[j]));
      }
      uint4 uh{hh[0] | (hh[1] << 16), hh[2] | (hh[3] << 16),
               hh[4] | (hh[5] << 16), hh[6] | (hh[7] << 16)};
      uint4 ul{ll[0] | (ll[1] << 16), ll[2] | (ll[3] << 16),
               ll[4] | (ll[5] << 16), ll[6] | (ll[7] << 16)};
      short* b = sx + ii * 6912 + r * 576 + slot * 16 + gg * 8;
      *(uint4*)b = uh;
      *(uint4*)(b + 3456) = ul;
    }
  }
  __syncthreads();

  // --- Phase 2: MFMA loop (2 output rows/wave), permuted weight icb ---
  f32x16 accA0, accB0, accA1, accB1;
#pragma unroll
  for (int i = 0; i < 16; ++i) { accA0[i] = 0.f; accB0[i] = 0.f; accA1[i] = 0.f; accB1[i] = 0.f; }

#pragma unroll
  for (int ii = 0; ii < NICB; ++ii) {
    const int icb = kg + 6 * ii;
#pragma unroll
    for (int tap = 0; tap < 9; ++tap) {
      const int dy = tap / 3, dx = tap % 3;
      const int sbase = ii * 6912 + (2 * rp + dy) * 576 + ((lane & 31) + dx) * 16 + g * 8;
      bf16x8 xh0 = *(const bf16x8*)&sx[sbase];
      bf16x8 xl0 = *(const bf16x8*)&sx[sbase + 3456];
      bf16x8 xh1 = *(const bf16x8*)&sx[sbase + 576];
      bf16x8 xl1 = *(const bf16x8*)&sx[sbase + 3456 + 576];
      long wi = ((long)((mt * 9 + tap) * ICBT + icb)) * 512 + lane * 8;
      bf16x8 wh = *(const bf16x8*)(whi + wi);
      bf16x8 wl = *(const bf16x8*)(wlo + wi);
      accA0 = __builtin_amdgcn_mfma_f32_32x32x16_bf16(wh, xh0, accA0, 0, 0, 0);
      accA1 = __builtin_amdgcn_mfma_f32_32x32x16_bf16(wh, xh1, accA1, 0, 0, 0);
      accB0 = __builtin_amdgcn_mfma_f32_32x32x16_bf16(wl, xh0, accB0, 0, 0, 0);
      accB1 = __builtin_amdgcn_mfma_f32_32x32x16_bf16(wl, xh1, accB1, 0, 0, 0);
      accB0 = __builtin_amdgcn_mfma_f32_32x32x16_bf16(wh, xl0, accB0, 0, 0, 0);
      accB1 = __builtin_amdgcn_mfma_f32_32x32x16_bf16(wh, xl1, accB1, 0, 0, 0);
    }
  }

  int pxg = bx + (lane & 31);
  if (pxg < W_) {
    long b0 = ((long)z * HW_ + (long)(by4 + 2 * rp) * W_ + pxg) * 64 + mt * 32 + g * 4;
    long b1v = b0 + (long)W_ * 64;
    float* q0 = part1 + b0;
    float* q1 = part1 + b1v;
#pragma unroll
    for (int qq = 0; qq < 4; ++qq) {
      *(float4*)(q0 + qq * 8) = float4{accA0[qq*4+0] + accB0[qq*4+0], accA0[qq*4+1] + accB0[qq*4+1],
                                       accA0[qq*4+2] + accB0[qq*4+2], accA0[qq*4+3] + accB0[qq*4+3]};
      *(float4*)(q1 + qq * 8) = float4{accA1[qq*4+0] + accB1[qq*4+0], accA1[qq*4+1] + accB1[qq*4+1],
                                       accA1[qq*4+2] + accB1[qq*4+2], accA1[qq*4+3] + accB1[qq*4+3]};
    }
  }
}

// ---------------------------------------------------------------------------
// conv2f: fused combine1 + conv2 partial. Staging computes h1 on the fly
// from 6 pixel-packed conv1 partials (+b1, lrelu, hi/lo split -> LDS).
// ---------------------------------------------------------------------------
__global__ __launch_bounds__(256) void conv2f(
    const float* __restrict__ part1, const float* __restrict__ b1,
    const short* __restrict__ whi, const short* __restrict__ wlo,
    float* __restrict__ part2) {
  constexpr int ICBT = 4, KG1 = 6;
  __shared__ alignas(16) short sx[6912];
  const int tid  = threadIdx.x;
  const int lane = tid & 63;
  const int wid  = tid >> 6;
  const int mt   = wid & 1;
  const int rp   = wid >> 1;
  const int g    = (lane >> 5) & 1;
  const int bx   = blockIdx.x * 32;
  const int by4  = blockIdx.y * 4;
  const int z    = blockIdx.z;
  const int kg   = z & 3;          // icb = cg
  const int n    = z >> 2;
  const int cg   = kg;

  float4 bA = *(const float4*)(b1 + cg * 16);
  float4 bB = *(const float4*)(b1 + cg * 16 + 4);
  float4 bC = *(const float4*)(b1 + cg * 16 + 8);
  float4 bD = *(const float4*)(b1 + cg * 16 + 12);

  // --- Staging: h1 tile computed from partials ---
#pragma unroll
  for (int it = 0; it < 2; ++it) {
    int s = it * 256 + tid;
    if (s < 432) {
      int r = s / 72, k = s - r * 72;
      int slot = k >> 1, gg = k & 1;
      int gy = by4 + r - 1;
      int gx = bx + slot - 1;
      float v[8];
      if (((unsigned)gy < (unsigned)H_) && ((unsigned)gx < (unsigned)W_)) {
        float4 sa = gg ? bC : bA;
        float4 sb = gg ? bD : bB;
        v[0] = sa.x; v[1] = sa.y; v[2] = sa.z; v[3] = sa.w;
        v[4] = sb.x; v[5] = sb.y; v[6] = sb.z; v[7] = sb.w;
        long pxo = ((long)gy * W_ + gx) * 64 + cg * 16 + gg * 8;
#pragma unroll
        for (int k1 = 0; k1 < KG1; ++k1) {
          const float* q = part1 + (long)(n * KG1 + k1) * HW_ * 64 + pxo;
          float4 a = *(const float4*)q, b = *(const float4*)(q + 4);
          v[0] += a.x; v[1] += a.y; v[2] += a.z; v[3] += a.w;
          v[4] += b.x; v[5] += b.y; v[6] += b.z; v[7] += b.w;
        }
#pragma unroll
        for (int j = 0; j < 8; ++j) v[j] = v[j] > 0.f ? v[j] : v[j] * SLOPE_;
      } else {
#pragma unroll
        for (int j = 0; j < 8; ++j) v[j] = 0.f;
      }
      unsigned hh[8], ll[8];
#pragma unroll
      for (int j = 0; j < 8; ++j) {
        hh[j] = f2bf(v[j]);
        ll[j] = f2bf(v[j] - bf2f((unsigned short)hh[j]));
      }
      uint4 uh{hh[0] | (hh[1] << 16), hh[2] | (hh[3] << 16),
               hh[4] | (hh[5] << 16), hh[6] | (hh[7] << 16)};
      uint4 ul{ll[0] | (ll[1] << 16), ll[2] | (ll[3] << 16),
               ll[4] | (ll[5] << 16), ll[6] | (ll[7] << 16)};
      short* b = sx + r * 576 + slot * 16 + gg * 8;
      *(uint4*)b = uh;
      *(uint4*)(b + 3456) = ul;
    }
  }
  __syncthreads();

  // --- MFMA loop ---
  f32x16 accA0, accB0, accA1, accB1;
#pragma unroll
  for (int i = 0; i < 16; ++i) { accA0[i] = 0.f; accB0[i] = 0.f; accA1[i] = 0.f; accB1[i] = 0.f; }

#pragma unroll
  for (int tap = 0; tap < 9; ++tap) {
    const int dy = tap / 3, dx = tap % 3;
    const int sbase = (2 * rp + dy) * 576 + ((lane & 31) + dx) * 16 + g * 8;
    bf16x8 xh0 = *(const bf16x8*)&sx[sbase];
    bf16x8 xl0 = *(const bf16x8*)&sx[sbase + 3456];
    bf16x8 xh1 = *(const bf16x8*)&sx[sbase + 576];
    bf16x8 xl1 = *(const bf16x8*)&sx[sbase + 3456 + 576];
    long wi = ((long)((mt * 9 + tap) * ICBT + kg)) * 512 + lane * 8;
    bf16x8 wh = *(const bf16x8*)(whi + wi);
    bf16x8 wl = *(const bf16x8*)(wlo + wi);
    accA0 = __builtin_amdgcn_mfma_f32_32x32x16_bf16(wh, xh0, accA0, 0, 0, 0);
    accA1 = __builtin_amdgcn_mfma_f32_32x32x16_bf16(wh, xh1, accA1, 0, 0, 0);
    accB0 = __builtin_amdgcn_mfma_f32_32x32x16_bf16(wl, xh0, accB0, 0, 0, 0);
    accB1 = __builtin_amdgcn_mfma_f32_32x32x16_bf16(wl, xh1, accB1, 0, 0, 0);
    accB0 = __builtin_amdgcn_mfma_f32_32x32x16_bf16(wh, xl0, accB0, 0, 0, 0);
    accB1 = __builtin_amdgcn_mfma_f32_32x32x16_bf16(wh, xl1, accB1, 0, 0, 0);
  }

  int pxg = bx + (lane & 31);
  if (pxg < W_) {
    long b0 = ((long)z * HW_ + (long)(by4 + 2 * rp) * W_ + pxg) * 64 + mt * 32 + g * 4;
    long b1v = b0 + (long)W_ * 64;
    float* q0 = part2 + b0;
    float* q1 = part2 + b1v;
#pragma unroll
    for (int qq = 0; qq < 4; ++qq) {
      *(float4*)(q0 + qq * 8) = float4{accA0[qq*4+0] + accB0[qq*4+0], accA0[qq*4+1] + accB0[qq*4+1],
                                       accA0[qq*4+2] + accB0[qq*4+2], accA0[qq*4+3] + accB0[qq*4+3]};
      *(float4*)(q1 + qq * 8) = float4{accA1[qq*4+0] + accB1[qq*4+0], accA1[qq*4+1] + accB1[qq*4+1],
                                       accA1[qq*4+2] + accB1[qq*4+2], accA1[qq*4+3] + accB1[qq*4+3]};
    }
  }
}

// ---------------------------------------------------------------------------
// combine2p: final = sum_kg part2 + b2 + resid(Wf packed); writes Wf and
// NCHW d_out.
// ---------------------------------------------------------------------------
template <int KG>
__global__ __launch_bounds__(256) void combine2p(
    const float* __restrict__ part2, const float* __restrict__ bias,
    float* __restrict__ WfT,   // packed t-slice, n-stride NSTW_
    float* __restrict__ out) { // NCHW, t-slice offset pre-added
  __shared__ float sm[16][113];
  int bid = blockIdx.x;
  int y   = bid % H_;
  int cg  = (bid / H_) % 4;
  int n   = bid / (H_ * 4);
  int tid = threadIdx.x;
  if (tid < 224) {
    int px = tid >> 1, gg = tid & 1;
    const float* bp = bias + cg * 16 + gg * 8;
    float v[8];
#pragma unroll
    for (int j = 0; j < 8; ++j) v[j] = bp[j];
    long pxo = ((long)y * W_ + px) * 64 + cg * 16 + gg * 8;
#pragma unroll
    for (int k = 0; k < KG; ++k) {
      const float* q = part2 + (long)(n * KG + k) * HW_ * 64 + pxo;
      float4 a = *(const float4*)q, b = *(const float4*)(q + 4);
      v[0] += a.x; v[1] += a.y; v[2] += a.z; v[3] += a.w;
      v[4] += b.x; v[5] += b.y; v[6] += b.z; v[7] += b.w;
    }
    float* q = WfT + (long)n * NSTW_ + (long)cg * PHW_ + ((long)y * W_ + px) * 16 + gg * 8;
    float4 ra = *(const float4*)q, rb = *(const float4*)(q + 4);
    v[0] += ra.x; v[1] += ra.y; v[2] += ra.z; v[3] += ra.w;
    v[4] += rb.x; v[5] += rb.y; v[6] += rb.z; v[7] += rb.w;
    *(float4*)q = float4{v[0], v[1], v[2], v[3]};
    *(float4*)(q + 4) = float4{v[4], v[5], v[6], v[7]};
#pragma unroll
    for (int j = 0; j < 8; ++j) sm[gg * 8 + j][px] = v[j];
  }
  __syncthreads();
  for (int i = tid; i < 16 * 112; i += 256) {
    int c = i / 112, x = i - c * 112;
    out[(long)n * T_ * C_ * HW_ + (long)(cg * 16 + c) * HW_ + (long)y * W_ + x] = sm[c][x];
  }
}

// ---------------------------------------------------------------------------
// Host-side orchestration
// ---------------------------------------------------------------------------
constexpr int KG1 = 6;
constexpr int KG2 = 4;

struct Bufs {
  float* part1; float* part2; float* Wf; float4* coords;
  short *w1hi, *w1lo, *w2hi, *w2lo;
};

static void run_step(float* out, int t, bool fwd, int i,
                     const float* b1, const float* b2, const Bufs& B,
                     hipStream_t stream) {
  const float* currP = B.Wf + (long)t * 4 * PHW_;
  const float* p1P = nullptr;
  const float* p2P = nullptr;
  if (fwd) {
    if (t >= 1) p1P = B.Wf + (long)(t - 1) * 4 * PHW_;
    if (t >= 2) p2P = B.Wf + (long)(t - 2) * 4 * PHW_;
  } else {
    if (i >= 1) p1P = B.Wf + (long)(t + 1) * 4 * PHW_;
    if (i >= 2) p2P = B.Wf + (long)(t + 2) * 4 * PHW_;
  }
  int sid = fwd ? t : 12 + t;
  const float4* coords_t = B.coords + (long)sid * N_ * HW_;

  warp_conv1<<<dim3(4, 28, N_ * KG1), 256, 0, stream>>>(
      currP, p1P, p2P, coords_t, B.w1hi, B.w1lo, B.part1);
  conv2f<<<dim3(4, 28, N_ * KG2), 256, 0, stream>>>(
      B.part1, b1, B.w2hi, B.w2lo, B.part2);
  combine2p<KG2><<<N_ * 4 * H_, 256, 0, stream>>>(
      B.part2, b2, B.Wf + (long)t * 4 * PHW_, out + (long)t * C_ * HW_);
}

extern "C" void kernel_launch(void* const* d_in, const int* in_sizes, int n_in,
                              void* d_out, int out_size, void* d_ws, size_t ws_size,
                              hipStream_t stream) {
  const float* feats = (const float*)d_in[0];
  const float* fflow = (const float*)d_in[1];
  const float* bflow = (const float*)d_in[2];
  const float* W1 = (const float*)d_in[3];
  const float* b1 = (const float*)d_in[4];
  const float* W2 = (const float*)d_in[5];
  const float* b2 = (const float*)d_in[6];
  float* out = (float*)d_out;

  char* p = (char*)d_ws;
  auto carve = [&](size_t bytes) {
    void* r = (void*)p;
    p += (bytes + 255) & ~(size_t)255;
    return r;
  };
  Bufs B;
  B.part1  = (float*)carve(sizeof(float) * (size_t)KG1 * N_ * HW_ * 64);
  B.part2  = (float*)carve(sizeof(float) * (size_t)KG2 * N_ * HW_ * 64);
  B.Wf     = (float*)carve(sizeof(float) * (size_t)N_ * T_ * 4 * PHW_);
  B.coords = (float4*)carve(sizeof(float4) * (size_t)24 * N_ * HW_);
  B.w1hi   = (short*)carve(2 * (size_t)(2 * 9 * 12 * 64 * 8));
  B.w1lo   = (short*)carve(2 * (size_t)(2 * 9 * 12 * 64 * 8));
  B.w2hi   = (short*)carve(2 * (size_t)(2 * 9 * 4 * 64 * 8));
  B.w2lo   = (short*)carve(2 * (size_t)(2 * 9 * 4 * 64 * 8));

  // Prologue: pack feats; all warp coords (flow-only dependent); weights.
  pack_feats<<<N_ * T_ * 4 * H_, 256, 0, stream>>>(feats, B.Wf);
  {
    long total = (long)24 * N_ * HW_;
    warp_coords_all<<<(int)((total + 255) / 256), 256, 0, stream>>>(fflow, bflow, B.coords);
  }
  pack_w<<<(2 * 9 * 12 * 64 * 8 + 255) / 256, 256, 0, stream>>>(W1, B.w1hi, B.w1lo, 12);
  pack_w<<<(2 * 9 * 4 * 64 * 8 + 255) / 256, 256, 0, stream>>>(W2, B.w2hi, B.w2lo, 4);

  for (int t = 0; t < T_; ++t)
    run_step(out, t, true, t, b1, b2, B, stream);
  for (int i = 0; i < T_; ++i) {
    int t = T_ - 1 - i;
    run_step(out, t, false, i, b1, b2, B, stream);
  }
}

// Round 23
// 1571.522 us; speedup vs baseline: 1.0635x; 1.0109x over previous
//
#include <hip/hip_runtime.h>

// Problem constants (fixed by reference)
constexpr int N_ = 2, T_ = 12, C_ = 64, H_ = 112, W_ = 112;
constexpr int HW_ = H_ * W_;
constexpr float SLOPE_ = 0.1f;
// Packed fp32 working-feats layout: [n][t][cg 0..3][HW][16ch]
constexpr int PHW_ = HW_ * 16;
constexpr long NSTW_ = (long)T_ * 4 * PHW_;

typedef short bf16x8 __attribute__((ext_vector_type(8)));
typedef float f32x16 __attribute__((ext_vector_type(16)));

__device__ __forceinline__ unsigned short f2bf(float f) {
  unsigned u = __float_as_uint(f);
  unsigned r = (u + 0x7fffu + ((u >> 16) & 1u)) >> 16;
  return (unsigned short)r;
}
__device__ __forceinline__ float bf2f(unsigned short h) {
  return __uint_as_float(((unsigned)h) << 16);
}

// ---------------------------------------------------------------------------
// Scalar bilinear (2-channel flow for f2_tot), zero-pad outside.
// ---------------------------------------------------------------------------
__device__ __forceinline__ float samp_one(const float* __restrict__ img, int y, int x) {
  if ((unsigned)x < (unsigned)W_ && (unsigned)y < (unsigned)H_)
    return img[y * W_ + x];
  return 0.f;
}

__device__ __forceinline__ float bilin(const float* __restrict__ img, float vx, float vy) {
  float x0f = floorf(vx), y0f = floorf(vy);
  int x0 = (int)x0f, y0 = (int)y0f;
  float wx = vx - x0f, wy = vy - y0f;
  float g00 = samp_one(img, y0,     x0);
  float g01 = samp_one(img, y0,     x0 + 1);
  float g10 = samp_one(img, y0 + 1, x0);
  float g11 = samp_one(img, y0 + 1, x0 + 1);
  return g00 * (1.f - wx) * (1.f - wy)
       + g01 * wx * (1.f - wy)
       + g10 * (1.f - wx) * wy
       + g11 * wx * wy;
}

// 8-channel bilinear from the packed layout: corner = 2 coalesced float4.
__device__ __forceinline__ void bilin8p(const float* __restrict__ sp, int gg,
                                        float vx, float vy, float* __restrict__ v) {
  float x0f = floorf(vx), y0f = floorf(vy);
  int x0 = (int)x0f, y0 = (int)y0f;
  float wx = vx - x0f, wy = vy - y0f;
  float w00 = (1.f - wx) * (1.f - wy), w01 = wx * (1.f - wy);
  float w10 = (1.f - wx) * wy,         w11 = wx * wy;
  bool bx0 = (unsigned)x0 < (unsigned)W_, bx1 = (unsigned)(x0 + 1) < (unsigned)W_;
  bool by0 = (unsigned)y0 < (unsigned)H_, by1 = (unsigned)(y0 + 1) < (unsigned)H_;
  float m00 = (bx0 && by0) ? w00 : 0.f;
  float m01 = (bx1 && by0) ? w01 : 0.f;
  float m10 = (bx0 && by1) ? w10 : 0.f;
  float m11 = (bx1 && by1) ? w11 : 0.f;
  int cx0 = min(max(x0, 0), W_ - 1), cx1 = min(max(x0 + 1, 0), W_ - 1);
  int cy0 = min(max(y0, 0), H_ - 1), cy1 = min(max(y0 + 1, 0), H_ - 1);
  const float* q00 = sp + ((long)cy0 * W_ + cx0) * 16 + gg * 8;
  const float* q01 = sp + ((long)cy0 * W_ + cx1) * 16 + gg * 8;
  const float* q10 = sp + ((long)cy1 * W_ + cx0) * 16 + gg * 8;
  const float* q11 = sp + ((long)cy1 * W_ + cx1) * 16 + gg * 8;
  float4 a00 = *(const float4*)q00, b00 = *(const float4*)(q00 + 4);
  float4 a01 = *(const float4*)q01, b01 = *(const float4*)(q01 + 4);
  float4 a10 = *(const float4*)q10, b10 = *(const float4*)(q10 + 4);
  float4 a11 = *(const float4*)q11, b11 = *(const float4*)(q11 + 4);
  const float* p00 = (const float*)&a00;
  const float* p01 = (const float*)&a01;
  const float* p10 = (const float*)&a10;
  const float* p11 = (const float*)&a11;
#pragma unroll
  for (int j = 0; j < 4; ++j)
    v[j] = p00[j] * m00 + p01[j] * m01 + p10[j] * m10 + p11[j] * m11;
  p00 = (const float*)&b00; p01 = (const float*)&b01;
  p10 = (const float*)&b10; p11 = (const float*)&b11;
#pragma unroll
  for (int j = 0; j < 4; ++j)
    v[4 + j] = p00[j] * m00 + p01[j] * m01 + p10[j] * m10 + p11[j] * m11;
}

// ---------------------------------------------------------------------------
// warp_coords_all: coords depend ONLY on input flows -> all 24 (dir,t) sets
// once in the prologue. coords[sid][n][hw] = {vx1, vy1, vx2, vy2}.
// ---------------------------------------------------------------------------
__global__ __launch_bounds__(256) void warp_coords_all(
    const float* __restrict__ fflow, const float* __restrict__ bflow,
    float4* __restrict__ coords) {
  long id = (long)blockIdx.x * 256 + threadIdx.x;
  long total = (long)24 * N_ * HW_;
  if (id >= total) return;
  int hw  = (int)(id % HW_);
  int n   = (int)((id / HW_) % N_);
  int sid = (int)(id / ((long)N_ * HW_));
  bool fwd = sid < 12;
  int t = fwd ? sid : sid - 12;
  const float* flows = fwd ? fflow : bflow;
  const float* f1 = nullptr;
  const float* f2 = nullptr;
  if (fwd) {
    if (t >= 1) f1 = flows + (long)(t - 1) * 2 * HW_;
    if (t >= 2) f2 = flows + (long)(t - 2) * 2 * HW_;
  } else {
    if (t <= 10) f1 = flows + (long)(t + 1) * 2 * HW_;
    if (t <= 9)  f2 = flows + (long)(t + 2) * 2 * HW_;
  }
  if (!f1) return;
  int x = hw % W_, y = hw / W_;
  const float* f1n = f1 + (long)n * T_ * 2 * HW_;
  float ax = (float)x + f1n[hw];
  float ay = (float)y + f1n[HW_ + hw];
  float vx2 = 0.f, vy2 = 0.f;
  if (f2) {
    const float* f2n = f2 + (long)n * T_ * 2 * HW_;
    vx2 = ax + bilin(f2n,       ax, ay);
    vy2 = ay + bilin(f2n + HW_, ax, ay);
  }
  coords[((long)sid * N_ + n) * HW_ + hw] = float4{ax, ay, vx2, vy2};
}

// ---------------------------------------------------------------------------
// pack_feats: NCHW fp32 feats -> packed Wf [n][t][cg][HW][16].
// float4 reads + 32B-contiguous writes.
// ---------------------------------------------------------------------------
__global__ __launch_bounds__(256) void pack_feats(
    const float* __restrict__ feats, float* __restrict__ Wf) {
  __shared__ float sm[16][113];
  int bid = blockIdx.x;
  int y   = bid % H_;
  int cg  = (bid / H_) % 4;
  int nt  = bid / (H_ * 4);
  int tid = threadIdx.x;
  const float* src = feats + ((long)nt * C_ + cg * 16) * HW_ + (long)y * W_;
  for (int its = tid; its < 448; its += 256) {
    int c = its / 28, xq = its - c * 28;
    float4 a = *(const float4*)(src + (long)c * HW_ + xq * 4);
    sm[c][xq * 4 + 0] = a.x; sm[c][xq * 4 + 1] = a.y;
    sm[c][xq * 4 + 2] = a.z; sm[c][xq * 4 + 3] = a.w;
  }
  __syncthreads();
  if (tid < 224) {
    int px = tid >> 1, gg = tid & 1;
    float* dst = Wf + ((long)nt * 4 + cg) * PHW_ + ((long)y * W_ + px) * 16 + gg * 8;
    float4 a{sm[gg * 8 + 0][px], sm[gg * 8 + 1][px], sm[gg * 8 + 2][px], sm[gg * 8 + 3][px]};
    float4 b{sm[gg * 8 + 4][px], sm[gg * 8 + 5][px], sm[gg * 8 + 6][px], sm[gg * 8 + 7][px]};
    *(float4*)dst = a;
    *(float4*)(dst + 4) = b;
  }
}

// ---------------------------------------------------------------------------
// pack_w: W (64, IC, 3, 3) fp32 -> MFMA A-fragment order, split hi/lo bf16.
// ---------------------------------------------------------------------------
__global__ __launch_bounds__(256) void pack_w(
    const float* __restrict__ W, short* __restrict__ whi, short* __restrict__ wlo,
    int ICBC) {
  int id = blockIdx.x * 256 + threadIdx.x;
  int total = 2 * 9 * ICBC * 64 * 8;
  if (id >= total) return;
  int r    = id & 7;
  int lane = (id >> 3) & 63;
  int rest = id >> 9;
  int icb  = rest % ICBC;
  int mtt  = rest / ICBC;
  int tap  = mtt % 9;
  int mt   = mtt / 9;
  int oc = mt * 32 + (lane & 31);
  int ic = icb * 16 + ((lane >> 5) << 3) + r;
  int ky = tap / 3, kx = tap % 3;
  int IC = ICBC * 16;
  float v = W[(((long)oc * IC + ic) * 3 + ky) * 3 + kx];
  unsigned short h = f2bf(v);
  unsigned short l = f2bf(v - bf2f(h));
  whi[id] = (short)h;
  wlo[id] = (short)l;
}

// ---------------------------------------------------------------------------
// warp_conv1: fused warp+pack+conv1 partial. KG1=6, icbs {kg, kg+6},
// precomputed coords (1 float4 -> 8 corner float4s).
// ---------------------------------------------------------------------------
__global__ __launch_bounds__(256) void warp_conv1(
    const float* __restrict__ currP,
    const float* __restrict__ p1P,
    const float* __restrict__ p2P,
    const float4* __restrict__ coords,   // set base: [n][HW]
    const short* __restrict__ whi, const short* __restrict__ wlo,
    float* __restrict__ part1) {
  constexpr int ICBT = 12, KG = 6, NICB = 2;
  __shared__ alignas(16) short sx[NICB * 6912];   // 13824 B
  const int tid  = threadIdx.x;
  const int lane = tid & 63;
  const int wid  = tid >> 6;
  const int mt   = wid & 1;
  const int rp   = wid >> 1;
  const int g    = (lane >> 5) & 1;
  const int bx   = blockIdx.x * 32;
  const int by4  = blockIdx.y * 4;
  const int z    = blockIdx.z;
  const int kg   = z % KG;
  const int n    = z / KG;
  const long fnp = (long)n * NSTW_;

  const float* srcs[3] = { currP, p1P ? p1P : currP, p2P ? p2P : currP };
  const bool wf[3] = { false, p1P != nullptr, p2P != nullptr };

  // --- Phase 1: warp into LDS (sample s = [ii][r 0..5][k 0..71]) ---
#pragma unroll
  for (int it = 0; it < 4; ++it) {
    int s = it * 256 + tid;
    if (s < NICB * 432) {
      int ii  = s / 432;
      int rem = s - ii * 432;
      int r   = rem / 72;
      int k   = rem - r * 72;
      int slot = k >> 1, gg = k & 1;
      int gy = by4 + r - 1;
      int gx = bx + slot - 1;
      int icb = kg + 6 * ii;            // {kg, kg+6}
      int stype = icb >> 2;
      int cg  = icb & 3;
      const float* sp = srcs[stype] + fnp + (long)cg * PHW_;
      float v[8];
      bool inimg = ((unsigned)gy < (unsigned)H_) && ((unsigned)gx < (unsigned)W_);
      if (!inimg) {
#pragma unroll
        for (int j = 0; j < 8; ++j) v[j] = 0.f;
      } else if (!wf[stype]) {
        const float* q = sp + ((long)gy * W_ + gx) * 16 + gg * 8;
        float4 a = *(const float4*)q, b = *(const float4*)(q + 4);
        v[0] = a.x; v[1] = a.y; v[2] = a.z; v[3] = a.w;
        v[4] = b.x; v[5] = b.y; v[6] = b.z; v[7] = b.w;
      } else {
        float4 c = coords[(long)n * HW_ + (long)gy * W_ + gx];
        float vx = (stype == 1) ? c.x : c.z;
        float vy = (stype == 1) ? c.y : c.w;
        bilin8p(sp, gg, vx, vy, v);
      }
      unsigned hh[8], ll[8];
#pragma unroll
      for (int j = 0; j < 8; ++j) {
        hh[j] = f2bf(v[j]);
        ll[j] = f2bf(v[j] - bf2f((unsigned short)hh[j]));
      }
      uint4 uh{hh[0] | (hh[1] << 16), hh[2] | (hh[3] << 16),
               hh[4] | (hh[5] << 16), hh[6] | (hh[7] << 16)};
      uint4 ul{ll[0] | (ll[1] << 16), ll[2] | (ll[3] << 16),
               ll[4] | (ll[5] << 16), ll[6] | (ll[7] << 16)};
      short* b = sx + ii * 6912 + r * 576 + slot * 16 + gg * 8;
      *(uint4*)b = uh;
      *(uint4*)(b + 3456) = ul;
    }
  }
  __syncthreads();

  // --- Phase 2: MFMA loop (2 output rows/wave), permuted weight icb ---
  f32x16 accA0, accB0, accA1, accB1;
#pragma unroll
  for (int i = 0; i < 16; ++i) { accA0[i] = 0.f; accB0[i] = 0.f; accA1[i] = 0.f; accB1[i] = 0.f; }

#pragma unroll
  for (int ii = 0; ii < NICB; ++ii) {
    const int icb = kg + 6 * ii;
#pragma unroll
    for (int tap = 0; tap < 9; ++tap) {
      const int dy = tap / 3, dx = tap % 3;
      const int sbase = ii * 6912 + (2 * rp + dy) * 576 + ((lane & 31) + dx) * 16 + g * 8;
      bf16x8 xh0 = *(const bf16x8*)&sx[sbase];
      bf16x8 xl0 = *(const bf16x8*)&sx[sbase + 3456];
      bf16x8 xh1 = *(const bf16x8*)&sx[sbase + 576];
      bf16x8 xl1 = *(const bf16x8*)&sx[sbase + 3456 + 576];
      long wi = ((long)((mt * 9 + tap) * ICBT + icb)) * 512 + lane * 8;
      bf16x8 wh = *(const bf16x8*)(whi + wi);
      bf16x8 wl = *(const bf16x8*)(wlo + wi);
      accA0 = __builtin_amdgcn_mfma_f32_32x32x16_bf16(wh, xh0, accA0, 0, 0, 0);
      accA1 = __builtin_amdgcn_mfma_f32_32x32x16_bf16(wh, xh1, accA1, 0, 0, 0);
      accB0 = __builtin_amdgcn_mfma_f32_32x32x16_bf16(wl, xh0, accB0, 0, 0, 0);
      accB1 = __builtin_amdgcn_mfma_f32_32x32x16_bf16(wl, xh1, accB1, 0, 0, 0);
      accB0 = __builtin_amdgcn_mfma_f32_32x32x16_bf16(wh, xl0, accB0, 0, 0, 0);
      accB1 = __builtin_amdgcn_mfma_f32_32x32x16_bf16(wh, xl1, accB1, 0, 0, 0);
    }
  }

  int pxg = bx + (lane & 31);
  if (pxg < W_) {
    long b0 = ((long)z * HW_ + (long)(by4 + 2 * rp) * W_ + pxg) * 64 + mt * 32 + g * 4;
    long b1v = b0 + (long)W_ * 64;
    float* q0 = part1 + b0;
    float* q1 = part1 + b1v;
#pragma unroll
    for (int qq = 0; qq < 4; ++qq) {
      *(float4*)(q0 + qq * 8) = float4{accA0[qq*4+0] + accB0[qq*4+0], accA0[qq*4+1] + accB0[qq*4+1],
                                       accA0[qq*4+2] + accB0[qq*4+2], accA0[qq*4+3] + accB0[qq*4+3]};
      *(float4*)(q1 + qq * 8) = float4{accA1[qq*4+0] + accB1[qq*4+0], accA1[qq*4+1] + accB1[qq*4+1],
                                       accA1[qq*4+2] + accB1[qq*4+2], accA1[qq*4+3] + accB1[qq*4+3]};
    }
  }
}

// ---------------------------------------------------------------------------
// conv2f: fused combine1 + conv2 partial. Staging computes h1 on the fly
// from 6 pixel-packed conv1 partials (+b1, lrelu, hi/lo split -> LDS).
// ---------------------------------------------------------------------------
__global__ __launch_bounds__(256) void conv2f(
    const float* __restrict__ part1, const float* __restrict__ b1,
    const short* __restrict__ whi, const short* __restrict__ wlo,
    float* __restrict__ part2) {
  constexpr int ICBT = 4, KG1 = 6;
  __shared__ alignas(16) short sx[6912];
  const int tid  = threadIdx.x;
  const int lane = tid & 63;
  const int wid  = tid >> 6;
  const int mt   = wid & 1;
  const int rp   = wid >> 1;
  const int g    = (lane >> 5) & 1;
  const int bx   = blockIdx.x * 32;
  const int by4  = blockIdx.y * 4;
  const int z    = blockIdx.z;
  const int kg   = z & 3;          // icb = cg
  const int n    = z >> 2;
  const int cg   = kg;

  float4 bA = *(const float4*)(b1 + cg * 16);
  float4 bB = *(const float4*)(b1 + cg * 16 + 4);
  float4 bC = *(const float4*)(b1 + cg * 16 + 8);
  float4 bD = *(const float4*)(b1 + cg * 16 + 12);

  // --- Staging: h1 tile computed from partials ---
#pragma unroll
  for (int it = 0; it < 2; ++it) {
    int s = it * 256 + tid;
    if (s < 432) {
      int r = s / 72, k = s - r * 72;
      int slot = k >> 1, gg = k & 1;
      int gy = by4 + r - 1;
      int gx = bx + slot - 1;
      float v[8];
      if (((unsigned)gy < (unsigned)H_) && ((unsigned)gx < (unsigned)W_)) {
        float4 sa = gg ? bC : bA;
        float4 sb = gg ? bD : bB;
        v[0] = sa.x; v[1] = sa.y; v[2] = sa.z; v[3] = sa.w;
        v[4] = sb.x; v[5] = sb.y; v[6] = sb.z; v[7] = sb.w;
        long pxo = ((long)gy * W_ + gx) * 64 + cg * 16 + gg * 8;
#pragma unroll
        for (int k1 = 0; k1 < KG1; ++k1) {
          const float* q = part1 + (long)(n * KG1 + k1) * HW_ * 64 + pxo;
          float4 a = *(const float4*)q, b = *(const float4*)(q + 4);
          v[0] += a.x; v[1] += a.y; v[2] += a.z; v[3] += a.w;
          v[4] += b.x; v[5] += b.y; v[6] += b.z; v[7] += b.w;
        }
#pragma unroll
        for (int j = 0; j < 8; ++j) v[j] = v[j] > 0.f ? v[j] : v[j] * SLOPE_;
      } else {
#pragma unroll
        for (int j = 0; j < 8; ++j) v[j] = 0.f;
      }
      unsigned hh[8], ll[8];
#pragma unroll
      for (int j = 0; j < 8; ++j) {
        hh[j] = f2bf(v[j]);
        ll[j] = f2bf(v[j] - bf2f((unsigned short)hh[j]));
      }
      uint4 uh{hh[0] | (hh[1] << 16), hh[2] | (hh[3] << 16),
               hh[4] | (hh[5] << 16), hh[6] | (hh[7] << 16)};
      uint4 ul{ll[0] | (ll[1] << 16), ll[2] | (ll[3] << 16),
               ll[4] | (ll[5] << 16), ll[6] | (ll[7] << 16)};
      short* b = sx + r * 576 + slot * 16 + gg * 8;
      *(uint4*)b = uh;
      *(uint4*)(b + 3456) = ul;
    }
  }
  __syncthreads();

  // --- MFMA loop ---
  f32x16 accA0, accB0, accA1, accB1;
#pragma unroll
  for (int i = 0; i < 16; ++i) { accA0[i] = 0.f; accB0[i] = 0.f; accA1[i] = 0.f; accB1[i] = 0.f; }

#pragma unroll
  for (int tap = 0; tap < 9; ++tap) {
    const int dy = tap / 3, dx = tap % 3;
    const int sbase = (2 * rp + dy) * 576 + ((lane & 31) + dx) * 16 + g * 8;
    bf16x8 xh0 = *(const bf16x8*)&sx[sbase];
    bf16x8 xl0 = *(const bf16x8*)&sx[sbase + 3456];
    bf16x8 xh1 = *(const bf16x8*)&sx[sbase + 576];
    bf16x8 xl1 = *(const bf16x8*)&sx[sbase + 3456 + 576];
    long wi = ((long)((mt * 9 + tap) * ICBT + kg)) * 512 + lane * 8;
    bf16x8 wh = *(const bf16x8*)(whi + wi);
    bf16x8 wl = *(const bf16x8*)(wlo + wi);
    accA0 = __builtin_amdgcn_mfma_f32_32x32x16_bf16(wh, xh0, accA0, 0, 0, 0);
    accA1 = __builtin_amdgcn_mfma_f32_32x32x16_bf16(wh, xh1, accA1, 0, 0, 0);
    accB0 = __builtin_amdgcn_mfma_f32_32x32x16_bf16(wl, xh0, accB0, 0, 0, 0);
    accB1 = __builtin_amdgcn_mfma_f32_32x32x16_bf16(wl, xh1, accB1, 0, 0, 0);
    accB0 = __builtin_amdgcn_mfma_f32_32x32x16_bf16(wh, xl0, accB0, 0, 0, 0);
    accB1 = __builtin_amdgcn_mfma_f32_32x32x16_bf16(wh, xl1, accB1, 0, 0, 0);
  }

  int pxg = bx + (lane & 31);
  if (pxg < W_) {
    long b0 = ((long)z * HW_ + (long)(by4 + 2 * rp) * W_ + pxg) * 64 + mt * 32 + g * 4;
    long b1v = b0 + (long)W_ * 64;
    float* q0 = part2 + b0;
    float* q1 = part2 + b1v;
#pragma unroll
    for (int qq = 0; qq < 4; ++qq) {
      *(float4*)(q0 + qq * 8) = float4{accA0[qq*4+0] + accB0[qq*4+0], accA0[qq*4+1] + accB0[qq*4+1],
                                       accA0[qq*4+2] + accB0[qq*4+2], accA0[qq*4+3] + accB0[qq*4+3]};
      *(float4*)(q1 + qq * 8) = float4{accA1[qq*4+0] + accB1[qq*4+0], accA1[qq*4+1] + accB1[qq*4+1],
                                       accA1[qq*4+2] + accB1[qq*4+2], accA1[qq*4+3] + accB1[qq*4+3]};
    }
  }
}

// ---------------------------------------------------------------------------
// combine2p: final = sum_kg part2 + b2 + resid(Wf packed); always updates the
// packed working slice Wf. WOUT selects the NCHW d_out write: the forward
// pass's out[t] writes are DEAD (bwd overwrites all of them, and the
// recurrence reads only Wf) -> fwd instantiates WOUT=false, skipping the LDS
// transpose + 6.4MB NCHW store per step.
// ---------------------------------------------------------------------------
template <int KG, bool WOUT>
__global__ __launch_bounds__(256) void combine2p(
    const float* __restrict__ part2, const float* __restrict__ bias,
    float* __restrict__ WfT,   // packed t-slice, n-stride NSTW_
    float* __restrict__ out) { // NCHW, t-slice offset pre-added (unused if !WOUT)
  __shared__ float sm[16][113];
  int bid = blockIdx.x;
  int y   = bid % H_;
  int cg  = (bid / H_) % 4;
  int n   = bid / (H_ * 4);
  int tid = threadIdx.x;
  if (tid < 224) {
    int px = tid >> 1, gg = tid & 1;
    const float* bp = bias + cg * 16 + gg * 8;
    float v[8];
#pragma unroll
    for (int j = 0; j < 8; ++j) v[j] = bp[j];
    long pxo = ((long)y * W_ + px) * 64 + cg * 16 + gg * 8;
#pragma unroll
    for (int k = 0; k < KG; ++k) {
      const float* q = part2 + (long)(n * KG + k) * HW_ * 64 + pxo;
      float4 a = *(const float4*)q, b = *(const float4*)(q + 4);
      v[0] += a.x; v[1] += a.y; v[2] += a.z; v[3] += a.w;
      v[4] += b.x; v[5] += b.y; v[6] += b.z; v[7] += b.w;
    }
    float* q = WfT + (long)n * NSTW_ + (long)cg * PHW_ + ((long)y * W_ + px) * 16 + gg * 8;
    float4 ra = *(const float4*)q, rb = *(const float4*)(q + 4);
    v[0] += ra.x; v[1] += ra.y; v[2] += ra.z; v[3] += ra.w;
    v[4] += rb.x; v[5] += rb.y; v[6] += rb.z; v[7] += rb.w;
    *(float4*)q = float4{v[0], v[1], v[2], v[3]};
    *(float4*)(q + 4) = float4{v[4], v[5], v[6], v[7]};
    if (WOUT) {
#pragma unroll
      for (int j = 0; j < 8; ++j) sm[gg * 8 + j][px] = v[j];
    }
  }
  if (WOUT) {
    __syncthreads();
    for (int i = tid; i < 16 * 112; i += 256) {
      int c = i / 112, x = i - c * 112;
      out[(long)n * T_ * C_ * HW_ + (long)(cg * 16 + c) * HW_ + (long)y * W_ + x] = sm[c][x];
    }
  }
}

// ---------------------------------------------------------------------------
// Host-side orchestration
// ---------------------------------------------------------------------------
constexpr int KG1 = 6;
constexpr int KG2 = 4;

struct Bufs {
  float* part1; float* part2; float* Wf; float4* coords;
  short *w1hi, *w1lo, *w2hi, *w2lo;
};

static void run_step(float* out, int t, bool fwd, int i,
                     const float* b1, const float* b2, const Bufs& B,
                     hipStream_t stream) {
  const float* currP = B.Wf + (long)t * 4 * PHW_;
  const float* p1P = nullptr;
  const float* p2P = nullptr;
  if (fwd) {
    if (t >= 1) p1P = B.Wf + (long)(t - 1) * 4 * PHW_;
    if (t >= 2) p2P = B.Wf + (long)(t - 2) * 4 * PHW_;
  } else {
    if (i >= 1) p1P = B.Wf + (long)(t + 1) * 4 * PHW_;
    if (i >= 2) p2P = B.Wf + (long)(t + 2) * 4 * PHW_;
  }
  int sid = fwd ? t : 12 + t;
  const float4* coords_t = B.coords + (long)sid * N_ * HW_;

  warp_conv1<<<dim3(4, 28, N_ * KG1), 256, 0, stream>>>(
      currP, p1P, p2P, coords_t, B.w1hi, B.w1lo, B.part1);
  conv2f<<<dim3(4, 28, N_ * KG2), 256, 0, stream>>>(
      B.part1, b1, B.w2hi, B.w2lo, B.part2);
  if (fwd) {
    combine2p<KG2, false><<<N_ * 4 * H_, 256, 0, stream>>>(
        B.part2, b2, B.Wf + (long)t * 4 * PHW_, out + (long)t * C_ * HW_);
  } else {
    combine2p<KG2, true><<<N_ * 4 * H_, 256, 0, stream>>>(
        B.part2, b2, B.Wf + (long)t * 4 * PHW_, out + (long)t * C_ * HW_);
  }
}

extern "C" void kernel_launch(void* const* d_in, const int* in_sizes, int n_in,
                              void* d_out, int out_size, void* d_ws, size_t ws_size,
                              hipStream_t stream) {
  const float* feats = (const float*)d_in[0];
  const float* fflow = (const float*)d_in[1];
  const float* bflow = (const float*)d_in[2];
  const float* W1 = (const float*)d_in[3];
  const float* b1 = (const float*)d_in[4];
  const float* W2 = (const float*)d_in[5];
  const float* b2 = (const float*)d_in[6];
  float* out = (float*)d_out;

  char* p = (char*)d_ws;
  auto carve = [&](size_t bytes) {
    void* r = (void*)p;
    p += (bytes + 255) & ~(size_t)255;
    return r;
  };
  Bufs B;
  B.part1  = (float*)carve(sizeof(float) * (size_t)KG1 * N_ * HW_ * 64);
  B.part2  = (float*)carve(sizeof(float) * (size_t)KG2 * N_ * HW_ * 64);
  B.Wf     = (float*)carve(sizeof(float) * (size_t)N_ * T_ * 4 * PHW_);
  B.coords = (float4*)carve(sizeof(float4) * (size_t)24 * N_ * HW_);
  B.w1hi   = (short*)carve(2 * (size_t)(2 * 9 * 12 * 64 * 8));
  B.w1lo   = (short*)carve(2 * (size_t)(2 * 9 * 12 * 64 * 8));
  B.w2hi   = (short*)carve(2 * (size_t)(2 * 9 * 4 * 64 * 8));
  B.w2lo   = (short*)carve(2 * (size_t)(2 * 9 * 4 * 64 * 8));

  // Prologue: pack feats; all warp coords (flow-only dependent); weights.
  pack_feats<<<N_ * T_ * 4 * H_, 256, 0, stream>>>(feats, B.Wf);
  {
    long total = (long)24 * N_ * HW_;
    warp_coords_all<<<(int)((total + 255) / 256), 256, 0, stream>>>(fflow, bflow, B.coords);
  }
  pack_w<<<(2 * 9 * 12 * 64 * 8 + 255) / 256, 256, 0, stream>>>(W1, B.w1hi, B.w1lo, 12);
  pack_w<<<(2 * 9 * 4 * 64 * 8 + 255) / 256, 256, 0, stream>>>(W2, B.w2hi, B.w2lo, 4);

  for (int t = 0; t < T_; ++t)
    run_step(out, t, true, t, b1, b2, B, stream);
  for (int i = 0; i < T_; ++i) {
    int t = T_ - 1 - i;
    run_step(out, t, false, i, b1, b2, B, stream);
  }
}

// Round 24
// 1570.883 us; speedup vs baseline: 1.0640x; 1.0004x over previous
//
#include <hip/hip_runtime.h>

// Problem constants (fixed by reference)
constexpr int N_ = 2, T_ = 12, C_ = 64, H_ = 112, W_ = 112;
constexpr int HW_ = H_ * W_;
constexpr float SLOPE_ = 0.1f;
// Packed fp32 working-feats layout: [n][t][cg 0..3][HW][16ch]
constexpr int PHW_ = HW_ * 16;
constexpr long NSTW_ = (long)T_ * 4 * PHW_;

typedef short bf16x8 __attribute__((ext_vector_type(8)));
typedef float f32x16 __attribute__((ext_vector_type(16)));

__device__ __forceinline__ unsigned short f2bf(float f) {
  unsigned u = __float_as_uint(f);
  unsigned r = (u + 0x7fffu + ((u >> 16) & 1u)) >> 16;
  return (unsigned short)r;
}
__device__ __forceinline__ float bf2f(unsigned short h) {
  return __uint_as_float(((unsigned)h) << 16);
}

// ---------------------------------------------------------------------------
// Scalar bilinear (2-channel flow for f2_tot), zero-pad outside.
// ---------------------------------------------------------------------------
__device__ __forceinline__ float samp_one(const float* __restrict__ img, int y, int x) {
  if ((unsigned)x < (unsigned)W_ && (unsigned)y < (unsigned)H_)
    return img[y * W_ + x];
  return 0.f;
}

__device__ __forceinline__ float bilin(const float* __restrict__ img, float vx, float vy) {
  float x0f = floorf(vx), y0f = floorf(vy);
  int x0 = (int)x0f, y0 = (int)y0f;
  float wx = vx - x0f, wy = vy - y0f;
  float g00 = samp_one(img, y0,     x0);
  float g01 = samp_one(img, y0,     x0 + 1);
  float g10 = samp_one(img, y0 + 1, x0);
  float g11 = samp_one(img, y0 + 1, x0 + 1);
  return g00 * (1.f - wx) * (1.f - wy)
       + g01 * wx * (1.f - wy)
       + g10 * (1.f - wx) * wy
       + g11 * wx * wy;
}

// 8-channel bilinear from the packed layout: corner = 2 coalesced float4.
__device__ __forceinline__ void bilin8p(const float* __restrict__ sp, int gg,
                                        float vx, float vy, float* __restrict__ v) {
  float x0f = floorf(vx), y0f = floorf(vy);
  int x0 = (int)x0f, y0 = (int)y0f;
  float wx = vx - x0f, wy = vy - y0f;
  float w00 = (1.f - wx) * (1.f - wy), w01 = wx * (1.f - wy);
  float w10 = (1.f - wx) * wy,         w11 = wx * wy;
  bool bx0 = (unsigned)x0 < (unsigned)W_, bx1 = (unsigned)(x0 + 1) < (unsigned)W_;
  bool by0 = (unsigned)y0 < (unsigned)H_, by1 = (unsigned)(y0 + 1) < (unsigned)H_;
  float m00 = (bx0 && by0) ? w00 : 0.f;
  float m01 = (bx1 && by0) ? w01 : 0.f;
  float m10 = (bx0 && by1) ? w10 : 0.f;
  float m11 = (bx1 && by1) ? w11 : 0.f;
  int cx0 = min(max(x0, 0), W_ - 1), cx1 = min(max(x0 + 1, 0), W_ - 1);
  int cy0 = min(max(y0, 0), H_ - 1), cy1 = min(max(y0 + 1, 0), H_ - 1);
  const float* q00 = sp + ((long)cy0 * W_ + cx0) * 16 + gg * 8;
  const float* q01 = sp + ((long)cy0 * W_ + cx1) * 16 + gg * 8;
  const float* q10 = sp + ((long)cy1 * W_ + cx0) * 16 + gg * 8;
  const float* q11 = sp + ((long)cy1 * W_ + cx1) * 16 + gg * 8;
  float4 a00 = *(const float4*)q00, b00 = *(const float4*)(q00 + 4);
  float4 a01 = *(const float4*)q01, b01 = *(const float4*)(q01 + 4);
  float4 a10 = *(const float4*)q10, b10 = *(const float4*)(q10 + 4);
  float4 a11 = *(const float4*)q11, b11 = *(const float4*)(q11 + 4);
  const float* p00 = (const float*)&a00;
  const float* p01 = (const float*)&a01;
  const float* p10 = (const float*)&a10;
  const float* p11 = (const float*)&a11;
#pragma unroll
  for (int j = 0; j < 4; ++j)
    v[j] = p00[j] * m00 + p01[j] * m01 + p10[j] * m10 + p11[j] * m11;
  p00 = (const float*)&b00; p01 = (const float*)&b01;
  p10 = (const float*)&b10; p11 = (const float*)&b11;
#pragma unroll
  for (int j = 0; j < 4; ++j)
    v[4 + j] = p00[j] * m00 + p01[j] * m01 + p10[j] * m10 + p11[j] * m11;
}

// ---------------------------------------------------------------------------
// warp_coords_all: coords depend ONLY on input flows -> all 24 (dir,t) sets
// once in the prologue. coords[sid][n][hw] = {vx1, vy1, vx2, vy2}.
// ---------------------------------------------------------------------------
__global__ __launch_bounds__(256) void warp_coords_all(
    const float* __restrict__ fflow, const float* __restrict__ bflow,
    float4* __restrict__ coords) {
  long id = (long)blockIdx.x * 256 + threadIdx.x;
  long total = (long)24 * N_ * HW_;
  if (id >= total) return;
  int hw  = (int)(id % HW_);
  int n   = (int)((id / HW_) % N_);
  int sid = (int)(id / ((long)N_ * HW_));
  bool fwd = sid < 12;
  int t = fwd ? sid : sid - 12;
  const float* flows = fwd ? fflow : bflow;
  const float* f1 = nullptr;
  const float* f2 = nullptr;
  if (fwd) {
    if (t >= 1) f1 = flows + (long)(t - 1) * 2 * HW_;
    if (t >= 2) f2 = flows + (long)(t - 2) * 2 * HW_;
  } else {
    if (t <= 10) f1 = flows + (long)(t + 1) * 2 * HW_;
    if (t <= 9)  f2 = flows + (long)(t + 2) * 2 * HW_;
  }
  if (!f1) return;
  int x = hw % W_, y = hw / W_;
  const float* f1n = f1 + (long)n * T_ * 2 * HW_;
  float ax = (float)x + f1n[hw];
  float ay = (float)y + f1n[HW_ + hw];
  float vx2 = 0.f, vy2 = 0.f;
  if (f2) {
    const float* f2n = f2 + (long)n * T_ * 2 * HW_;
    vx2 = ax + bilin(f2n,       ax, ay);
    vy2 = ay + bilin(f2n + HW_, ax, ay);
  }
  coords[((long)sid * N_ + n) * HW_ + hw] = float4{ax, ay, vx2, vy2};
}

// ---------------------------------------------------------------------------
// pack_feats: NCHW fp32 feats -> packed Wf [n][t][cg][HW][16].
// float4 reads + 32B-contiguous writes.
// ---------------------------------------------------------------------------
__global__ __launch_bounds__(256) void pack_feats(
    const float* __restrict__ feats, float* __restrict__ Wf) {
  __shared__ float sm[16][113];
  int bid = blockIdx.x;
  int y   = bid % H_;
  int cg  = (bid / H_) % 4;
  int nt  = bid / (H_ * 4);
  int tid = threadIdx.x;
  const float* src = feats + ((long)nt * C_ + cg * 16) * HW_ + (long)y * W_;
  for (int its = tid; its < 448; its += 256) {
    int c = its / 28, xq = its - c * 28;
    float4 a = *(const float4*)(src + (long)c * HW_ + xq * 4);
    sm[c][xq * 4 + 0] = a.x; sm[c][xq * 4 + 1] = a.y;
    sm[c][xq * 4 + 2] = a.z; sm[c][xq * 4 + 3] = a.w;
  }
  __syncthreads();
  if (tid < 224) {
    int px = tid >> 1, gg = tid & 1;
    float* dst = Wf + ((long)nt * 4 + cg) * PHW_ + ((long)y * W_ + px) * 16 + gg * 8;
    float4 a{sm[gg * 8 + 0][px], sm[gg * 8 + 1][px], sm[gg * 8 + 2][px], sm[gg * 8 + 3][px]};
    float4 b{sm[gg * 8 + 4][px], sm[gg * 8 + 5][px], sm[gg * 8 + 6][px], sm[gg * 8 + 7][px]};
    *(float4*)dst = a;
    *(float4*)(dst + 4) = b;
  }
}

// ---------------------------------------------------------------------------
// pack_w: W (64, IC, 3, 3) fp32 -> MFMA A-fragment order, split hi/lo bf16.
// ---------------------------------------------------------------------------
__global__ __launch_bounds__(256) void pack_w(
    const float* __restrict__ W, short* __restrict__ whi, short* __restrict__ wlo,
    int ICBC) {
  int id = blockIdx.x * 256 + threadIdx.x;
  int total = 2 * 9 * ICBC * 64 * 8;
  if (id >= total) return;
  int r    = id & 7;
  int lane = (id >> 3) & 63;
  int rest = id >> 9;
  int icb  = rest % ICBC;
  int mtt  = rest / ICBC;
  int tap  = mtt % 9;
  int mt   = mtt / 9;
  int oc = mt * 32 + (lane & 31);
  int ic = icb * 16 + ((lane >> 5) << 3) + r;
  int ky = tap / 3, kx = tap % 3;
  int IC = ICBC * 16;
  float v = W[(((long)oc * IC + ic) * 3 + ky) * 3 + kx];
  unsigned short h = f2bf(v);
  unsigned short l = f2bf(v - bf2f(h));
  whi[id] = (short)h;
  wlo[id] = (short)l;
}

// ---------------------------------------------------------------------------
// warp_conv1: fused warp+pack+conv1 partial. KG1=6, icbs {kg, kg+6},
// precomputed coords. r24: part1 layout is KG-INTERLEAVED
// part1[n][HW][kg][64] so conv2f's 6-partial pixel sum is one contiguous
// 1.5KB block (old [z][HW][64] put the 6 reads 6.4MB apart -> no line
// reuse across the 1.69x halo re-reads).
// ---------------------------------------------------------------------------
__global__ __launch_bounds__(256) void warp_conv1(
    const float* __restrict__ currP,
    const float* __restrict__ p1P,
    const float* __restrict__ p2P,
    const float4* __restrict__ coords,   // set base: [n][HW]
    const short* __restrict__ whi, const short* __restrict__ wlo,
    float* __restrict__ part1) {
  constexpr int ICBT = 12, KG = 6, NICB = 2;
  __shared__ alignas(16) short sx[NICB * 6912];   // 13824 B
  const int tid  = threadIdx.x;
  const int lane = tid & 63;
  const int wid  = tid >> 6;
  const int mt   = wid & 1;
  const int rp   = wid >> 1;
  const int g    = (lane >> 5) & 1;
  const int bx   = blockIdx.x * 32;
  const int by4  = blockIdx.y * 4;
  const int z    = blockIdx.z;
  const int kg   = z % KG;
  const int n    = z / KG;
  const long fnp = (long)n * NSTW_;

  const float* srcs[3] = { currP, p1P ? p1P : currP, p2P ? p2P : currP };
  const bool wf[3] = { false, p1P != nullptr, p2P != nullptr };

  // --- Phase 1: warp into LDS (sample s = [ii][r 0..5][k 0..71]) ---
#pragma unroll
  for (int it = 0; it < 4; ++it) {
    int s = it * 256 + tid;
    if (s < NICB * 432) {
      int ii  = s / 432;
      int rem = s - ii * 432;
      int r   = rem / 72;
      int k   = rem - r * 72;
      int slot = k >> 1, gg = k & 1;
      int gy = by4 + r - 1;
      int gx = bx + slot - 1;
      int icb = kg + 6 * ii;            // {kg, kg+6}
      int stype = icb >> 2;
      int cg  = icb & 3;
      const float* sp = srcs[stype] + fnp + (long)cg * PHW_;
      float v[8];
      bool inimg = ((unsigned)gy < (unsigned)H_) && ((unsigned)gx < (unsigned)W_);
      if (!inimg) {
#pragma unroll
        for (int j = 0; j < 8; ++j) v[j] = 0.f;
      } else if (!wf[stype]) {
        const float* q = sp + ((long)gy * W_ + gx) * 16 + gg * 8;
        float4 a = *(const float4*)q, b = *(const float4*)(q + 4);
        v[0] = a.x; v[1] = a.y; v[2] = a.z; v[3] = a.w;
        v[4] = b.x; v[5] = b.y; v[6] = b.z; v[7] = b.w;
      } else {
        float4 c = coords[(long)n * HW_ + (long)gy * W_ + gx];
        float vx = (stype == 1) ? c.x : c.z;
        float vy = (stype == 1) ? c.y : c.w;
        bilin8p(sp, gg, vx, vy, v);
      }
      unsigned hh[8], ll[8];
#pragma unroll
      for (int j = 0; j < 8; ++j) {
        hh[j] = f2bf(v[j]);
        ll[j] = f2bf(v[j] - bf2f((unsigned short)hh[j]));
      }
      uint4 uh{hh[0] | (hh[1] << 16), hh[2] | (hh[3] << 16),
               hh[4] | (hh[5] << 16), hh[6] | (hh[7] << 16)};
      uint4 ul{ll[0] | (ll[1] << 16), ll[2] | (ll[3] << 16),
               ll[4] | (ll[5] << 16), ll[6] | (ll[7] << 16)};
      short* b = sx + ii * 6912 + r * 576 + slot * 16 + gg * 8;
      *(uint4*)b = uh;
      *(uint4*)(b + 3456) = ul;
    }
  }
  __syncthreads();

  // --- Phase 2: MFMA loop (2 output rows/wave), permuted weight icb ---
  f32x16 accA0, accB0, accA1, accB1;
#pragma unroll
  for (int i = 0; i < 16; ++i) { accA0[i] = 0.f; accB0[i] = 0.f; accA1[i] = 0.f; accB1[i] = 0.f; }

#pragma unroll
  for (int ii = 0; ii < NICB; ++ii) {
    const int icb = kg + 6 * ii;
#pragma unroll
    for (int tap = 0; tap < 9; ++tap) {
      const int dy = tap / 3, dx = tap % 3;
      const int sbase = ii * 6912 + (2 * rp + dy) * 576 + ((lane & 31) + dx) * 16 + g * 8;
      bf16x8 xh0 = *(const bf16x8*)&sx[sbase];
      bf16x8 xl0 = *(const bf16x8*)&sx[sbase + 3456];
      bf16x8 xh1 = *(const bf16x8*)&sx[sbase + 576];
      bf16x8 xl1 = *(const bf16x8*)&sx[sbase + 3456 + 576];
      long wi = ((long)((mt * 9 + tap) * ICBT + icb)) * 512 + lane * 8;
      bf16x8 wh = *(const bf16x8*)(whi + wi);
      bf16x8 wl = *(const bf16x8*)(wlo + wi);
      accA0 = __builtin_amdgcn_mfma_f32_32x32x16_bf16(wh, xh0, accA0, 0, 0, 0);
      accA1 = __builtin_amdgcn_mfma_f32_32x32x16_bf16(wh, xh1, accA1, 0, 0, 0);
      accB0 = __builtin_amdgcn_mfma_f32_32x32x16_bf16(wl, xh0, accB0, 0, 0, 0);
      accB1 = __builtin_amdgcn_mfma_f32_32x32x16_bf16(wl, xh1, accB1, 0, 0, 0);
      accB0 = __builtin_amdgcn_mfma_f32_32x32x16_bf16(wh, xl0, accB0, 0, 0, 0);
      accB1 = __builtin_amdgcn_mfma_f32_32x32x16_bf16(wh, xl1, accB1, 0, 0, 0);
    }
  }

  int pxg = bx + (lane & 31);
  if (pxg < W_) {
    // part1[n][HW][kg][64]
    long b0 = (((long)n * HW_ + (long)(by4 + 2 * rp) * W_ + pxg) * KG + kg) * 64 + mt * 32 + g * 4;
    long b1v = b0 + (long)W_ * KG * 64;
    float* q0 = part1 + b0;
    float* q1 = part1 + b1v;
#pragma unroll
    for (int qq = 0; qq < 4; ++qq) {
      *(float4*)(q0 + qq * 8) = float4{accA0[qq*4+0] + accB0[qq*4+0], accA0[qq*4+1] + accB0[qq*4+1],
                                       accA0[qq*4+2] + accB0[qq*4+2], accA0[qq*4+3] + accB0[qq*4+3]};
      *(float4*)(q1 + qq * 8) = float4{accA1[qq*4+0] + accB1[qq*4+0], accA1[qq*4+1] + accB1[qq*4+1],
                                       accA1[qq*4+2] + accB1[qq*4+2], accA1[qq*4+3] + accB1[qq*4+3]};
    }
  }
}

// ---------------------------------------------------------------------------
// conv2f: fused combine1 + conv2 partial. Staging computes h1 on the fly
// from the 6 KG-INTERLEAVED conv1 partials: one pixel's 6 kg-chunks are a
// contiguous 1.5KB block -> the halo-amplified re-reads hit cache lines.
// part2 likewise [n][HW][kg2][64].
// ---------------------------------------------------------------------------
__global__ __launch_bounds__(256) void conv2f(
    const float* __restrict__ part1, const float* __restrict__ b1,
    const short* __restrict__ whi, const short* __restrict__ wlo,
    float* __restrict__ part2) {
  constexpr int ICBT = 4, KG1 = 6, KG2 = 4;
  __shared__ alignas(16) short sx[6912];
  const int tid  = threadIdx.x;
  const int lane = tid & 63;
  const int wid  = tid >> 6;
  const int mt   = wid & 1;
  const int rp   = wid >> 1;
  const int g    = (lane >> 5) & 1;
  const int bx   = blockIdx.x * 32;
  const int by4  = blockIdx.y * 4;
  const int z    = blockIdx.z;
  const int kg   = z & 3;          // input icb = cg
  const int n    = z >> 2;
  const int cg   = kg;

  float4 bA = *(const float4*)(b1 + cg * 16);
  float4 bB = *(const float4*)(b1 + cg * 16 + 4);
  float4 bC = *(const float4*)(b1 + cg * 16 + 8);
  float4 bD = *(const float4*)(b1 + cg * 16 + 12);

  // --- Staging: h1 tile computed from partials ---
#pragma unroll
  for (int it = 0; it < 2; ++it) {
    int s = it * 256 + tid;
    if (s < 432) {
      int r = s / 72, k = s - r * 72;
      int slot = k >> 1, gg = k & 1;
      int gy = by4 + r - 1;
      int gx = bx + slot - 1;
      float v[8];
      if (((unsigned)gy < (unsigned)H_) && ((unsigned)gx < (unsigned)W_)) {
        float4 sa = gg ? bC : bA;
        float4 sb = gg ? bD : bB;
        v[0] = sa.x; v[1] = sa.y; v[2] = sa.z; v[3] = sa.w;
        v[4] = sb.x; v[5] = sb.y; v[6] = sb.z; v[7] = sb.w;
        long pxo = ((long)n * HW_ + (long)gy * W_ + gx) * (KG1 * 64) + cg * 16 + gg * 8;
#pragma unroll
        for (int k1 = 0; k1 < KG1; ++k1) {
          const float* q = part1 + pxo + (long)k1 * 64;
          float4 a = *(const float4*)q, b = *(const float4*)(q + 4);
          v[0] += a.x; v[1] += a.y; v[2] += a.z; v[3] += a.w;
          v[4] += b.x; v[5] += b.y; v[6] += b.z; v[7] += b.w;
        }
#pragma unroll
        for (int j = 0; j < 8; ++j) v[j] = v[j] > 0.f ? v[j] : v[j] * SLOPE_;
      } else {
#pragma unroll
        for (int j = 0; j < 8; ++j) v[j] = 0.f;
      }
      unsigned hh[8], ll[8];
#pragma unroll
      for (int j = 0; j < 8; ++j) {
        hh[j] = f2bf(v[j]);
        ll[j] = f2bf(v[j] - bf2f((unsigned short)hh[j]));
      }
      uint4 uh{hh[0] | (hh[1] << 16), hh[2] | (hh[3] << 16),
               hh[4] | (hh[5] << 16), hh[6] | (hh[7] << 16)};
      uint4 ul{ll[0] | (ll[1] << 16), ll[2] | (ll[3] << 16),
               ll[4] | (ll[5] << 16), ll[6] | (ll[7] << 16)};
      short* b = sx + r * 576 + slot * 16 + gg * 8;
      *(uint4*)b = uh;
      *(uint4*)(b + 3456) = ul;
    }
  }
  __syncthreads();

  // --- MFMA loop ---
  f32x16 accA0, accB0, accA1, accB1;
#pragma unroll
  for (int i = 0; i < 16; ++i) { accA0[i] = 0.f; accB0[i] = 0.f; accA1[i] = 0.f; accB1[i] = 0.f; }

#pragma unroll
  for (int tap = 0; tap < 9; ++tap) {
    const int dy = tap / 3, dx = tap % 3;
    const int sbase = (2 * rp + dy) * 576 + ((lane & 31) + dx) * 16 + g * 8;
    bf16x8 xh0 = *(const bf16x8*)&sx[sbase];
    bf16x8 xl0 = *(const bf16x8*)&sx[sbase + 3456];
    bf16x8 xh1 = *(const bf16x8*)&sx[sbase + 576];
    bf16x8 xl1 = *(const bf16x8*)&sx[sbase + 3456 + 576];
    long wi = ((long)((mt * 9 + tap) * ICBT + kg)) * 512 + lane * 8;
    bf16x8 wh = *(const bf16x8*)(whi + wi);
    bf16x8 wl = *(const bf16x8*)(wlo + wi);
    accA0 = __builtin_amdgcn_mfma_f32_32x32x16_bf16(wh, xh0, accA0, 0, 0, 0);
    accA1 = __builtin_amdgcn_mfma_f32_32x32x16_bf16(wh, xh1, accA1, 0, 0, 0);
    accB0 = __builtin_amdgcn_mfma_f32_32x32x16_bf16(wl, xh0, accB0, 0, 0, 0);
    accB1 = __builtin_amdgcn_mfma_f32_32x32x16_bf16(wl, xh1, accB1, 0, 0, 0);
    accB0 = __builtin_amdgcn_mfma_f32_32x32x16_bf16(wh, xl0, accB0, 0, 0, 0);
    accB1 = __builtin_amdgcn_mfma_f32_32x32x16_bf16(wh, xl1, accB1, 0, 0, 0);
  }

  int pxg = bx + (lane & 31);
  if (pxg < W_) {
    // part2[n][HW][kg][64]
    long b0 = (((long)n * HW_ + (long)(by4 + 2 * rp) * W_ + pxg) * KG2 + kg) * 64 + mt * 32 + g * 4;
    long b1v = b0 + (long)W_ * KG2 * 64;
    float* q0 = part2 + b0;
    float* q1 = part2 + b1v;
#pragma unroll
    for (int qq = 0; qq < 4; ++qq) {
      *(float4*)(q0 + qq * 8) = float4{accA0[qq*4+0] + accB0[qq*4+0], accA0[qq*4+1] + accB0[qq*4+1],
                                       accA0[qq*4+2] + accB0[qq*4+2], accA0[qq*4+3] + accB0[qq*4+3]};
      *(float4*)(q1 + qq * 8) = float4{accA1[qq*4+0] + accB1[qq*4+0], accA1[qq*4+1] + accB1[qq*4+1],
                                       accA1[qq*4+2] + accB1[qq*4+2], accA1[qq*4+3] + accB1[qq*4+3]};
    }
  }
}

// ---------------------------------------------------------------------------
// combine2p: final = sum_kg part2 + b2 + resid(Wf packed); always updates the
// packed working slice Wf. WOUT selects the NCHW d_out write (fwd writes are
// dead). part2 reads are now contiguous per pixel (4 kg-chunks, 1KB block).
// ---------------------------------------------------------------------------
template <int KG, bool WOUT>
__global__ __launch_bounds__(256) void combine2p(
    const float* __restrict__ part2, const float* __restrict__ bias,
    float* __restrict__ WfT,   // packed t-slice, n-stride NSTW_
    float* __restrict__ out) { // NCHW, t-slice offset pre-added (unused if !WOUT)
  __shared__ float sm[16][113];
  int bid = blockIdx.x;
  int y   = bid % H_;
  int cg  = (bid / H_) % 4;
  int n   = bid / (H_ * 4);
  int tid = threadIdx.x;
  if (tid < 224) {
    int px = tid >> 1, gg = tid & 1;
    const float* bp = bias + cg * 16 + gg * 8;
    float v[8];
#pragma unroll
    for (int j = 0; j < 8; ++j) v[j] = bp[j];
    long pxo = ((long)n * HW_ + (long)y * W_ + px) * (KG * 64) + cg * 16 + gg * 8;
#pragma unroll
    for (int k = 0; k < KG; ++k) {
      const float* q = part2 + pxo + (long)k * 64;
      float4 a = *(const float4*)q, b = *(const float4*)(q + 4);
      v[0] += a.x; v[1] += a.y; v[2] += a.z; v[3] += a.w;
      v[4] += b.x; v[5] += b.y; v[6] += b.z; v[7] += b.w;
    }
    float* q = WfT + (long)n * NSTW_ + (long)cg * PHW_ + ((long)y * W_ + px) * 16 + gg * 8;
    float4 ra = *(const float4*)q, rb = *(const float4*)(q + 4);
    v[0] += ra.x; v[1] += ra.y; v[2] += ra.z; v[3] += ra.w;
    v[4] += rb.x; v[5] += rb.y; v[6] += rb.z; v[7] += rb.w;
    *(float4*)q = float4{v[0], v[1], v[2], v[3]};
    *(float4*)(q + 4) = float4{v[4], v[5], v[6], v[7]};
    if (WOUT) {
#pragma unroll
      for (int j = 0; j < 8; ++j) sm[gg * 8 + j][px] = v[j];
    }
  }
  if (WOUT) {
    __syncthreads();
    for (int i = tid; i < 16 * 112; i += 256) {
      int c = i / 112, x = i - c * 112;
      out[(long)n * T_ * C_ * HW_ + (long)(cg * 16 + c) * HW_ + (long)y * W_ + x] = sm[c][x];
    }
  }
}

// ---------------------------------------------------------------------------
// Host-side orchestration
// ---------------------------------------------------------------------------
constexpr int KG1 = 6;
constexpr int KG2 = 4;

struct Bufs {
  float* part1; float* part2; float* Wf; float4* coords;
  short *w1hi, *w1lo, *w2hi, *w2lo;
};

static void run_step(float* out, int t, bool fwd, int i,
                     const float* b1, const float* b2, const Bufs& B,
                     hipStream_t stream) {
  const float* currP = B.Wf + (long)t * 4 * PHW_;
  const float* p1P = nullptr;
  const float* p2P = nullptr;
  if (fwd) {
    if (t >= 1) p1P = B.Wf + (long)(t - 1) * 4 * PHW_;
    if (t >= 2) p2P = B.Wf + (long)(t - 2) * 4 * PHW_;
  } else {
    if (i >= 1) p1P = B.Wf + (long)(t + 1) * 4 * PHW_;
    if (i >= 2) p2P = B.Wf + (long)(t + 2) * 4 * PHW_;
  }
  int sid = fwd ? t : 12 + t;
  const float4* coords_t = B.coords + (long)sid * N_ * HW_;

  warp_conv1<<<dim3(4, 28, N_ * KG1), 256, 0, stream>>>(
      currP, p1P, p2P, coords_t, B.w1hi, B.w1lo, B.part1);
  conv2f<<<dim3(4, 28, N_ * KG2), 256, 0, stream>>>(
      B.part1, b1, B.w2hi, B.w2lo, B.part2);
  if (fwd) {
    combine2p<KG2, false><<<N_ * 4 * H_, 256, 0, stream>>>(
        B.part2, b2, B.Wf + (long)t * 4 * PHW_, out + (long)t * C_ * HW_);
  } else {
    combine2p<KG2, true><<<N_ * 4 * H_, 256, 0, stream>>>(
        B.part2, b2, B.Wf + (long)t * 4 * PHW_, out + (long)t * C_ * HW_);
  }
}

extern "C" void kernel_launch(void* const* d_in, const int* in_sizes, int n_in,
                              void* d_out, int out_size, void* d_ws, size_t ws_size,
                              hipStream_t stream) {
  const float* feats = (const float*)d_in[0];
  const float* fflow = (const float*)d_in[1];
  const float* bflow = (const float*)d_in[2];
  const float* W1 = (const float*)d_in[3];
  const float* b1 = (const float*)d_in[4];
  const float* W2 = (const float*)d_in[5];
  const float* b2 = (const float*)d_in[6];
  float* out = (float*)d_out;

  char* p = (char*)d_ws;
  auto carve = [&](size_t bytes) {
    void* r = (void*)p;
    p += (bytes + 255) & ~(size_t)255;
    return r;
  };
  Bufs B;
  B.part1  = (float*)carve(sizeof(float) * (size_t)KG1 * N_ * HW_ * 64);
  B.part2  = (float*)carve(sizeof(float) * (size_t)KG2 * N_ * HW_ * 64);
  B.Wf     = (float*)carve(sizeof(float) * (size_t)N_ * T_ * 4 * PHW_);
  B.coords = (float4*)carve(sizeof(float4) * (size_t)24 * N_ * HW_);
  B.w1hi   = (short*)carve(2 * (size_t)(2 * 9 * 12 * 64 * 8));
  B.w1lo   = (short*)carve(2 * (size_t)(2 * 9 * 12 * 64 * 8));
  B.w2hi   = (short*)carve(2 * (size_t)(2 * 9 * 4 * 64 * 8));
  B.w2lo   = (short*)carve(2 * (size_t)(2 * 9 * 4 * 64 * 8));

  // Prologue: pack feats; all warp coords (flow-only dependent); weights.
  pack_feats<<<N_ * T_ * 4 * H_, 256, 0, stream>>>(feats, B.Wf);
  {
    long total = (long)24 * N_ * HW_;
    warp_coords_all<<<(int)((total + 255) / 256), 256, 0, stream>>>(fflow, bflow, B.coords);
  }
  pack_w<<<(2 * 9 * 12 * 64 * 8 + 255) / 256, 256, 0, stream>>>(W1, B.w1hi, B.w1lo, 12);
  pack_w<<<(2 * 9 * 4 * 64 * 8 + 255) / 256, 256, 0, stream>>>(W2, B.w2hi, B.w2lo, 4);

  for (int t = 0; t < T_; ++t)
    run_step(out, t, true, t, b1, b2, B, stream);
  for (int i = 0; i < T_; ++i) {
    int t = T_ - 1 - i;
    run_step(out, t, false, i, b1, b2, B, stream);
  }
}